// Round 3
// baseline (729.747 us; speedup 1.0000x reference)
//
#include <hip/hip_runtime.h>
#include <math.h>

// GCN: h = D^-1/2 (A+I) D^-1/2 (x W) + b, 3 layers + classifier.
// N = 100000 nodes, E = 3.2M edges, feats 128 -> 4 -> 4 -> 2 -> 4.
//
// Round 3: device-scope atomics measured at ~20 G/s (memory-side 32B
// transaction each, per-XCD L2s non-coherent). Replace them with
// workgroup-scope atomics into per-XCD partial histograms (indexed by
// HW_REG_XCC_ID) -- these complete in the local XCD L2 at ~cycle rate.
// Build becomes: count (2 L2 atomics/edge) -> scan (8-way prefix per node,
// turning partials into per-XCD cursors) -> place (1 L2 atomic/edge gives
// the exact ELL slot). Zero device-scope atomics on the hot path.

#define ELL_C   64
#define OVF_CAP 32768

__device__ __forceinline__ unsigned xcd_id() {
    unsigned x;
    asm("s_getreg_b32 %0, hwreg(HW_REG_XCC_ID)" : "=s"(x));
    return x & 7u;
}

// ---------------- shared kernels ----------------

__global__ __launch_bounds__(256) void zero_kernel(int* __restrict__ p, long count) {
    long i = (long)blockIdx.x * blockDim.x + threadIdx.x;
    if (i < count) p[i] = 0;
}

// x [n,128] @ W1 [128,4] -> Td1 [n,4], pre-scaled by dinv[v].
__global__ __launch_bounds__(256) void mm1_kernel(const float* __restrict__ x, const float* __restrict__ W1,
                                                  const float* __restrict__ dinv, float4* __restrict__ Td1, int n) {
    int gid  = blockIdx.x * blockDim.x + threadIdx.x;
    int lane = threadIdx.x & 63;
    int v    = gid >> 6;
    if (v >= n) return;
    const float x0 = x[(size_t)v * 128 + lane];
    const float x1 = x[(size_t)v * 128 + 64 + lane];
    float p0 = x0 * W1[lane * 4 + 0] + x1 * W1[(lane + 64) * 4 + 0];
    float p1 = x0 * W1[lane * 4 + 1] + x1 * W1[(lane + 64) * 4 + 1];
    float p2 = x0 * W1[lane * 4 + 2] + x1 * W1[(lane + 64) * 4 + 2];
    float p3 = x0 * W1[lane * 4 + 3] + x1 * W1[(lane + 64) * 4 + 3];
#pragma unroll
    for (int off = 32; off > 0; off >>= 1) {
        p0 += __shfl_xor(p0, off);
        p1 += __shfl_xor(p1, off);
        p2 += __shfl_xor(p2, off);
        p3 += __shfl_xor(p3, off);
    }
    if (lane == 0) {
        float d = dinv[v];
        Td1[v] = make_float4(p0 * d, p1 * d, p2 * d, p3 * d);
    }
}

__global__ __launch_bounds__(256) void ovf4_kernel(const int* __restrict__ ovfc, const int2* __restrict__ ovf,
                                                   const float4* __restrict__ Td, float* __restrict__ B) {
    int e = blockIdx.x * blockDim.x + threadIdx.x;
    int m = *ovfc; if (m > OVF_CAP) m = OVF_CAP;
    if (e >= m) return;
    int2 rc = ovf[e];
    float4 t = Td[rc.y];
    atomicAdd(&B[rc.x * 4 + 0], t.x);
    atomicAdd(&B[rc.x * 4 + 1], t.y);
    atomicAdd(&B[rc.x * 4 + 2], t.z);
    atomicAdd(&B[rc.x * 4 + 3], t.w);
}

__global__ __launch_bounds__(256) void ovf2_kernel(const int* __restrict__ ovfc, const int2* __restrict__ ovf,
                                                   const float2* __restrict__ Td, float* __restrict__ D) {
    int e = blockIdx.x * blockDim.x + threadIdx.x;
    int m = *ovfc; if (m > OVF_CAP) m = OVF_CAP;
    if (e >= m) return;
    int2 rc = ovf[e];
    float2 t = Td[rc.y];
    atomicAdd(&D[rc.x * 2 + 0], t.x);
    atomicAdd(&D[rc.x * 2 + 1], t.y);
}

// Pull aggregation + layer-1 epilogue: h1 = tanh(dinv*(sum + self) + b1), Td2 = (h1@W2)*dinv.
__global__ __launch_bounds__(256) void agg_node1(const int* __restrict__ cnt, const int* __restrict__ slots,
                                                 const float* __restrict__ dinv, const float4* __restrict__ Td1,
                                                 float4* __restrict__ B, const float* __restrict__ b1,
                                                 const float* __restrict__ W2, float4* __restrict__ Td2, int n) {
    int v = blockIdx.x * blockDim.x + threadIdx.x;
    if (v >= n) return;
    int k = cnt[v]; if (k > ELL_C) k = ELL_C;
    float4 s = B[v];                               // overflow partial (normally 0)
    for (int j = 0; j < k; ++j) {
        int c = slots[(size_t)j * n + v];
        float4 t = Td1[c];
        s.x += t.x; s.y += t.y; s.z += t.z; s.w += t.w;
    }
    float4 t0 = Td1[v];                            // self-loop
    s.x += t0.x; s.y += t0.y; s.z += t0.z; s.w += t0.w;
    float d = dinv[v];
    float h0 = tanhf(d * s.x + b1[0]);
    float h1 = tanhf(d * s.y + b1[1]);
    float h2 = tanhf(d * s.z + b1[2]);
    float h3 = tanhf(d * s.w + b1[3]);
    float4 o;
    o.x = (h0 * W2[0] + h1 * W2[4] + h2 * W2[8]  + h3 * W2[12]) * d;
    o.y = (h0 * W2[1] + h1 * W2[5] + h2 * W2[9]  + h3 * W2[13]) * d;
    o.z = (h0 * W2[2] + h1 * W2[6] + h2 * W2[10] + h3 * W2[14]) * d;
    o.w = (h0 * W2[3] + h1 * W2[7] + h2 * W2[11] + h3 * W2[15]) * d;
    Td2[v] = o;
    B[v] = make_float4(0.f, 0.f, 0.f, 0.f);        // reset for layer-2 overflow
}

__global__ __launch_bounds__(256) void agg_node2(const int* __restrict__ cnt, const int* __restrict__ slots,
                                                 const float* __restrict__ dinv, const float4* __restrict__ Td2,
                                                 const float4* __restrict__ B, const float* __restrict__ b2,
                                                 const float* __restrict__ W3, float2* __restrict__ Td3, int n) {
    int v = blockIdx.x * blockDim.x + threadIdx.x;
    if (v >= n) return;
    int k = cnt[v]; if (k > ELL_C) k = ELL_C;
    float4 s = B[v];
    for (int j = 0; j < k; ++j) {
        int c = slots[(size_t)j * n + v];
        float4 t = Td2[c];
        s.x += t.x; s.y += t.y; s.z += t.z; s.w += t.w;
    }
    float4 t0 = Td2[v];
    s.x += t0.x; s.y += t0.y; s.z += t0.z; s.w += t0.w;
    float d = dinv[v];
    float h0 = tanhf(d * s.x + b2[0]);
    float h1 = tanhf(d * s.y + b2[1]);
    float h2 = tanhf(d * s.z + b2[2]);
    float h3 = tanhf(d * s.w + b2[3]);
    float2 o;
    o.x = (h0 * W3[0] + h1 * W3[2] + h2 * W3[4] + h3 * W3[6]) * d;
    o.y = (h0 * W3[1] + h1 * W3[3] + h2 * W3[5] + h3 * W3[7]) * d;
    Td3[v] = o;
}

__global__ __launch_bounds__(256) void agg_node3(const int* __restrict__ cnt, const int* __restrict__ slots,
                                                 const float* __restrict__ dinv, const float2* __restrict__ Td3,
                                                 const float2* __restrict__ D, const float* __restrict__ b3,
                                                 const float* __restrict__ Wc, const float* __restrict__ bc,
                                                 float* __restrict__ out, int n) {
    int v = blockIdx.x * blockDim.x + threadIdx.x;
    if (v >= n) return;
    int k = cnt[v]; if (k > ELL_C) k = ELL_C;
    float2 s = D[v];
    for (int j = 0; j < k; ++j) {
        int c = slots[(size_t)j * n + v];
        float2 t = Td3[c];
        s.x += t.x; s.y += t.y;
    }
    float2 t0 = Td3[v];
    s.x += t0.x; s.y += t0.y;
    float d = dinv[v];
    float h0 = tanhf(d * s.x + b3[0]);
    float h1 = tanhf(d * s.y + b3[1]);
    float4 o;
    o.x = h0 * Wc[0] + h1 * Wc[4] + bc[0];
    o.y = h0 * Wc[1] + h1 * Wc[5] + bc[1];
    o.z = h0 * Wc[2] + h1 * Wc[6] + bc[2];
    o.w = h0 * Wc[3] + h1 * Wc[7] + bc[3];
    ((float4*)out)[v] = o;
    ((float2*)(out + (size_t)n * 4))[v] = make_float2(h0, h1);
}

// ---------------- fast path: per-XCD L2-scope atomic build ----------------

// Phase 1: per-XCD histograms. cof[x][r] = #edges into r from blocks on XCD x;
// dgx[x][c] = #edges out of c. Workgroup-scope atomics -> serviced in local L2.
__global__ __launch_bounds__(256) void count_kernel(const int* __restrict__ row, const int* __restrict__ col,
                                                    int* __restrict__ cof, int* __restrict__ dgx,
                                                    int n, int E) {
    int e = blockIdx.x * blockDim.x + threadIdx.x;
    if (e >= E) return;
    unsigned x = xcd_id();
    int r = row[e], c = col[e];
    __hip_atomic_fetch_add(&cof[(size_t)x * n + r], 1, __ATOMIC_RELAXED, __HIP_MEMORY_SCOPE_WORKGROUP);
    __hip_atomic_fetch_add(&dgx[(size_t)x * n + c], 1, __ATOMIC_RELAXED, __HIP_MEMORY_SCOPE_WORKGROUP);
}

// Phase 2: per-node 8-way exclusive prefix over XCD partials -> cursors; total -> cnt.
// Also dinv = rsqrt(deg+1).
__global__ __launch_bounds__(256) void scan_kernel(int* __restrict__ cof, const int* __restrict__ dgx,
                                                   int* __restrict__ cnt, float* __restrict__ dinv, int n) {
    int v = blockIdx.x * blockDim.x + threadIdx.x;
    if (v >= n) return;
    int run = 0;
#pragma unroll
    for (int x = 0; x < 8; ++x) {
        int t = cof[(size_t)x * n + v];
        cof[(size_t)x * n + v] = run;
        run += t;
    }
    cnt[v] = run;
    int d = 0;
#pragma unroll
    for (int x = 0; x < 8; ++x) d += dgx[(size_t)x * n + v];
    dinv[v] = rsqrtf((float)(d + 1));
}

// Phase 3: placement. The per-XCD cursor (pre-offset by phase 2) hands out the
// exact global ELL slot with one local-L2 atomic per edge.
__global__ __launch_bounds__(256) void place_kernel(const int* __restrict__ row, const int* __restrict__ col,
                                                    int* __restrict__ cof, int* __restrict__ slots,
                                                    int* __restrict__ ovfc, int2* __restrict__ ovf,
                                                    int n, int E) {
    int e = blockIdx.x * blockDim.x + threadIdx.x;
    if (e >= E) return;
    unsigned x = xcd_id();
    int r = row[e], c = col[e];
    int j = __hip_atomic_fetch_add(&cof[(size_t)x * n + r], 1, __ATOMIC_RELAXED, __HIP_MEMORY_SCOPE_WORKGROUP);
    if (j < ELL_C) {
        slots[(size_t)j * n + r] = c;
    } else {
        int i = atomicAdd(ovfc, 1);                // device scope, ~0 occurrences
        if (i < OVF_CAP) ovf[i] = make_int2(r, c);
    }
}

// ---------------- fallback build (round-2, device-scope atomics) ----------------

__global__ __launch_bounds__(256) void build_kernel(const int* __restrict__ row, const int* __restrict__ col,
                                                    int* __restrict__ deg, int* __restrict__ cnt,
                                                    int* __restrict__ slots, int* __restrict__ ovfc,
                                                    int2* __restrict__ ovf, int n, int E) {
    int e = blockIdx.x * blockDim.x + threadIdx.x;
    if (e >= E) return;
    int r = row[e], c = col[e];
    atomicAdd(&deg[c], 1);
    int pos = atomicAdd(&cnt[r], 1);
    if (pos < ELL_C) {
        slots[(size_t)pos * n + r] = c;
    } else {
        int i = atomicAdd(ovfc, 1);
        if (i < OVF_CAP) ovf[i] = make_int2(r, c);
    }
}

__global__ __launch_bounds__(256) void dinv2_kernel(const int* __restrict__ deg, float* __restrict__ dinv, int n) {
    int v = blockIdx.x * blockDim.x + threadIdx.x;
    if (v >= n) return;
    dinv[v] = rsqrtf((float)(deg[v] + 1));
}

extern "C" void kernel_launch(void* const* d_in, const int* in_sizes, int n_in,
                              void* d_out, int out_size, void* d_ws, size_t ws_size,
                              hipStream_t stream) {
    const float* x  = (const float*)d_in[0];
    const int*   ei = (const int*)  d_in[1];
    const float* W1 = (const float*)d_in[2];
    const float* b1 = (const float*)d_in[3];
    const float* W2 = (const float*)d_in[4];
    const float* b2 = (const float*)d_in[5];
    const float* W3 = (const float*)d_in[6];
    const float* b3 = (const float*)d_in[7];
    const float* Wc = (const float*)d_in[8];
    const float* bc = (const float*)d_in[9];

    const size_t n = (size_t)(in_sizes[0] / 128);
    const int    E = in_sizes[1] / 2;
    const int* row = ei;       // destinations (segment ids)
    const int* col = ei + E;   // sources (gather)

    const int nb_n  = (int)((n + 255) / 256);
    const int nb_e  = (E + 255) / 256;
    const int nb_mm = (int)((n * 64 + 255) / 256);
    const int nb_ov = OVF_CAP / 256;

    float* ws = (float*)d_ws;

    // fast-path layout (units of 4B):
    // A1 4n | A2 4n | C3 2n | Bv 4n | Dv 2n | dinv n | cnt n | cof 8n | dgx 8n | ovfc 4 | ovf 65536 | slots 64n
    size_t need_fast = (98 * n + 4 + 2 * OVF_CAP) * 4;
    size_t need_fb   = (83 * n + 4 + 2 * OVF_CAP) * 4;

    if (ws_size >= need_fast) {
        float* A1   = ws;
        float* A2   = A1 + 4 * n;
        float* C3   = A2 + 4 * n;
        float* Bv   = C3 + 2 * n;
        float* Dv   = Bv + 4 * n;
        float* dinv = Dv + 2 * n;
        int*   cnt  = (int*)(dinv + n);
        int*   cof  = cnt + n;
        int*   dgx  = cof + 8 * n;
        int*   ovfc = dgx + 8 * n;
        int2*  ovf  = (int2*)(ovfc + 4);
        int*   slots = (int*)(ovf + OVF_CAP);

        // zero [Bv .. ovfc+4): Bv(4n) Dv(2n) dinv(n) cnt(n) cof(8n) dgx(8n) ovfc(4) = 24n+4
        long zc = (long)(24 * n + 4);
        zero_kernel<<<(int)((zc + 255) / 256), 256, 0, stream>>>((int*)Bv, zc);

        count_kernel<<<nb_e, 256, 0, stream>>>(row, col, cof, dgx, (int)n, E);
        scan_kernel<<<nb_n, 256, 0, stream>>>(cof, dgx, cnt, dinv, (int)n);
        place_kernel<<<nb_e, 256, 0, stream>>>(row, col, cof, slots, ovfc, ovf, (int)n, E);

        mm1_kernel<<<nb_mm, 256, 0, stream>>>(x, W1, dinv, (float4*)A1, (int)n);

        ovf4_kernel<<<nb_ov, 256, 0, stream>>>(ovfc, ovf, (const float4*)A1, Bv);
        agg_node1<<<nb_n, 256, 0, stream>>>(cnt, slots, dinv, (const float4*)A1, (float4*)Bv, b1, W2, (float4*)A2, (int)n);

        ovf4_kernel<<<nb_ov, 256, 0, stream>>>(ovfc, ovf, (const float4*)A2, Bv);
        agg_node2<<<nb_n, 256, 0, stream>>>(cnt, slots, dinv, (const float4*)A2, (const float4*)Bv, b2, W3, (float2*)C3, (int)n);

        ovf2_kernel<<<nb_ov, 256, 0, stream>>>(ovfc, ovf, (const float2*)C3, Dv);
        agg_node3<<<nb_n, 256, 0, stream>>>(cnt, slots, dinv, (const float2*)C3, (const float2*)Dv, b3, Wc, bc, (float*)d_out, (int)n);
    } else {
        // fallback layout: A1 4n | A2 4n | C3 2n | Bv 4n | Dv 2n | dinv n | cnt n | deg n | ovfc 4 | ovf 65536 | slots 64n
        float* A1   = ws;
        float* A2   = A1 + 4 * n;
        float* C3   = A2 + 4 * n;
        float* Bv   = C3 + 2 * n;
        float* Dv   = Bv + 4 * n;
        float* dinv = Dv + 2 * n;
        int*   cnt  = (int*)(dinv + n);
        int*   deg  = cnt + n;
        int*   ovfc = deg + n;
        int2*  ovf  = (int2*)(ovfc + 4);
        int*   slots = (int*)(ovf + OVF_CAP);
        (void)need_fb;

        // zero [Bv .. ovfc+4): 4n+2n+n+n+n+4 = 9n+4
        long zc = (long)(9 * n + 4);
        zero_kernel<<<(int)((zc + 255) / 256), 256, 0, stream>>>((int*)Bv, zc);

        build_kernel<<<nb_e, 256, 0, stream>>>(row, col, deg, cnt, slots, ovfc, ovf, (int)n, E);
        dinv2_kernel<<<nb_n, 256, 0, stream>>>(deg, dinv, (int)n);

        mm1_kernel<<<nb_mm, 256, 0, stream>>>(x, W1, dinv, (float4*)A1, (int)n);

        ovf4_kernel<<<nb_ov, 256, 0, stream>>>(ovfc, ovf, (const float4*)A1, Bv);
        agg_node1<<<nb_n, 256, 0, stream>>>(cnt, slots, dinv, (const float4*)A1, (float4*)Bv, b1, W2, (float4*)A2, (int)n);

        ovf4_kernel<<<nb_ov, 256, 0, stream>>>(ovfc, ovf, (const float4*)A2, Bv);
        agg_node2<<<nb_n, 256, 0, stream>>>(cnt, slots, dinv, (const float4*)A2, (const float4*)Bv, b2, W3, (float2*)C3, (int)n);

        ovf2_kernel<<<nb_ov, 256, 0, stream>>>(ovfc, ovf, (const float2*)C3, Dv);
        agg_node3<<<nb_n, 256, 0, stream>>>(cnt, slots, dinv, (const float2*)C3, (const float2*)Dv, b3, Wc, bc, (float*)d_out, (int)n);
    }
}

// Round 4
// 444.789 us; speedup vs baseline: 1.6407x; 1.6407x over previous
//
#include <hip/hip_runtime.h>
#include <math.h>

// GCN: h = D^-1/2 (A+I) D^-1/2 (x W) + b, 3 layers + classifier.
// N = 100000 nodes, E = 3.2M edges, feats 128 -> 4 -> 4 -> 2 -> 4.
//
// Round 4 model: ANY random sub-line global op (device atomic, L2-scope
// atomic, or plain 4B scatter store) runs at ~20-30 G ops/s (32B memory-side
// transaction each; measured across rounds 1-3). So: eliminate per-edge
// random global ops. One partition pass bins edges by dest-range (256
// nodes/bucket) with LDS histograms + block-aggregated cursor reservations
// (~600K device atomics total, contiguous ~84B runs per bucket per block).
// deg comes from a per-bucket LDS histogram of the source-binned copy.
// Each agg pass: stream packed bucket edges sequentially, gather Td[c]
// (random READS from L2-resident 1.6MB table = cheap), accumulate in LDS
// (SoA, conflict-free), fused node epilogue. No ELL, no scan, no place.

#define OVF_CAP 32768
#define NBMAX   512      // max buckets (n <= 131072) for partition LDS arrays
#define CHUNK   8192     // edges per partition block
#define CAPB    11776    // bucket capacity (expected 8192 for uniform; 1.44x)

// ---------------- shared kernels ----------------

// x [n,128] @ W1 [128,4] -> Td1 [n,4], pre-scaled by dinv[v].
__global__ __launch_bounds__(256) void mm1_kernel(const float* __restrict__ x, const float* __restrict__ W1,
                                                  const float* __restrict__ dinv, float4* __restrict__ Td1, int n) {
    int gid  = blockIdx.x * blockDim.x + threadIdx.x;
    int lane = threadIdx.x & 63;
    int v    = gid >> 6;
    if (v >= n) return;
    const float x0 = x[(size_t)v * 128 + lane];
    const float x1 = x[(size_t)v * 128 + 64 + lane];
    float p0 = x0 * W1[lane * 4 + 0] + x1 * W1[(lane + 64) * 4 + 0];
    float p1 = x0 * W1[lane * 4 + 1] + x1 * W1[(lane + 64) * 4 + 1];
    float p2 = x0 * W1[lane * 4 + 2] + x1 * W1[(lane + 64) * 4 + 2];
    float p3 = x0 * W1[lane * 4 + 3] + x1 * W1[(lane + 64) * 4 + 3];
#pragma unroll
    for (int off = 32; off > 0; off >>= 1) {
        p0 += __shfl_xor(p0, off);
        p1 += __shfl_xor(p1, off);
        p2 += __shfl_xor(p2, off);
        p3 += __shfl_xor(p3, off);
    }
    if (lane == 0) {
        float d = dinv[v];
        Td1[v] = make_float4(p0 * d, p1 * d, p2 * d, p3 * d);
    }
}

__global__ __launch_bounds__(256) void ovf4_kernel(const int* __restrict__ ovfc, const int2* __restrict__ ovf,
                                                   const float4* __restrict__ Td, float* __restrict__ B) {
    int e = blockIdx.x * blockDim.x + threadIdx.x;
    int m = *ovfc; if (m > OVF_CAP) m = OVF_CAP;
    if (e >= m) return;
    int2 rc = ovf[e];
    float4 t = Td[rc.y];
    atomicAdd(&B[rc.x * 4 + 0], t.x);
    atomicAdd(&B[rc.x * 4 + 1], t.y);
    atomicAdd(&B[rc.x * 4 + 2], t.z);
    atomicAdd(&B[rc.x * 4 + 3], t.w);
}

__global__ __launch_bounds__(256) void ovf2_kernel(const int* __restrict__ ovfc, const int2* __restrict__ ovf,
                                                   const float2* __restrict__ Td, float* __restrict__ D) {
    int e = blockIdx.x * blockDim.x + threadIdx.x;
    int m = *ovfc; if (m > OVF_CAP) m = OVF_CAP;
    if (e >= m) return;
    int2 rc = ovf[e];
    float2 t = Td[rc.y];
    atomicAdd(&D[rc.x * 2 + 0], t.x);
    atomicAdd(&D[rc.x * 2 + 1], t.y);
}

// ---------------- fast path: bucket partition build ----------------

__global__ __launch_bounds__(256) void initc_kernel(int* __restrict__ curR, int* __restrict__ curC,
                                                    int* __restrict__ ovfRc, int* __restrict__ ovfCc, int B) {
    int i = blockIdx.x * blockDim.x + threadIdx.x;
    if (i == 0) { *ovfRc = 0; *ovfCc = 0; }
    if (i < B) { curR[i] = i * CAPB; curC[i] = i * CAPB; }
}

// One pass: bin edges by r>>8 into pairs[] (packed r_local<<24|c) and by c>>8
// into bufC[]. Block-aggregated reservations; writes land in contiguous runs.
__global__ __launch_bounds__(256) void part_kernel(const int* __restrict__ row, const int* __restrict__ col,
                                                   int* __restrict__ curR, int* __restrict__ curC,
                                                   int* __restrict__ pairs, int* __restrict__ bufC,
                                                   int* __restrict__ ovfRc, int2* __restrict__ ovfR,
                                                   int* __restrict__ ovfCc, int* __restrict__ ovfC,
                                                   int B, int E) {
    __shared__ int hR[NBMAX], hC[NBMAX], bR[NBMAX], bC[NBMAX];
    const int t = threadIdx.x;
    const long e0 = (long)blockIdx.x * CHUNK;
    for (int i = t; i < B; i += 256) { hR[i] = 0; hC[i] = 0; }
    __syncthreads();
    // phase 1: LDS histograms
#pragma unroll 4
    for (int k = 0; k < CHUNK / 256; ++k) {
        long e = e0 + (long)k * 256 + t;
        if (e < E) {
            atomicAdd(&hR[row[e] >> 8], 1);
            atomicAdd(&hC[col[e] >> 8], 1);
        }
    }
    __syncthreads();
    // phase 2: one device atomic per touched bucket
    for (int i = t; i < B; i += 256) {
        int nr = hR[i];
        bR[i] = nr ? atomicAdd(&curR[i], nr) : 0;
        hR[i] = 0;
        int nc = hC[i];
        bC[i] = nc ? atomicAdd(&curC[i], nc) : 0;
        hC[i] = 0;
    }
    __syncthreads();
    // phase 3: place into reserved runs
#pragma unroll 4
    for (int k = 0; k < CHUNK / 256; ++k) {
        long e = e0 + (long)k * 256 + t;
        if (e < E) {
            int r = row[e], c = col[e];
            int b = r >> 8;
            int pos = bR[b] + atomicAdd(&hR[b], 1);
            if (pos < (b + 1) * CAPB) {
                pairs[pos] = ((r & 255) << 24) | c;
            } else {
                int i = atomicAdd(ovfRc, 1);
                if (i < OVF_CAP) ovfR[i] = make_int2(r, c);
            }
            int bc2 = c >> 8;
            int posc = bC[bc2] + atomicAdd(&hC[bc2], 1);
            if (posc < (bc2 + 1) * CAPB) {
                bufC[posc] = c;
            } else {
                int i = atomicAdd(ovfCc, 1);
                if (i < OVF_CAP) ovfC[i] = c;
            }
        }
    }
}

// deg from source-binned copy: per-bucket LDS histogram, sequential write.
__global__ __launch_bounds__(256) void histo_kernel(const int* __restrict__ curC, const int* __restrict__ bufC,
                                                    int* __restrict__ deg, int n) {
    __shared__ int h[256];
    const int b = blockIdx.x, t = threadIdx.x;
    h[t] = 0;
    __syncthreads();
    int base = b * CAPB;
    int cnt = curC[b] - base; if (cnt > CAPB) cnt = CAPB;
    for (int k = t; k < cnt; k += 256) atomicAdd(&h[bufC[base + k] & 255], 1);
    __syncthreads();
    int v = b * 256 + t;
    if (v < n) deg[v] = h[t];
}

__global__ __launch_bounds__(256) void ovfc_deg_kernel(const int* __restrict__ ovfCc, const int* __restrict__ ovfC,
                                                       int* __restrict__ deg) {
    int i = blockIdx.x * blockDim.x + threadIdx.x;
    int m = *ovfCc; if (m > OVF_CAP) m = OVF_CAP;
    if (i >= m) return;
    atomicAdd(&deg[ovfC[i]], 1);
}

__global__ __launch_bounds__(256) void dinvz_kernel(const int* __restrict__ deg, float* __restrict__ dinv,
                                                    float4* __restrict__ Bv, float2* __restrict__ Dv, int n) {
    int v = blockIdx.x * blockDim.x + threadIdx.x;
    if (v >= n) return;
    dinv[v] = rsqrtf((float)(deg[v] + 1));
    Bv[v] = make_float4(0.f, 0.f, 0.f, 0.f);
    Dv[v] = make_float2(0.f, 0.f);
}

// agg pass 1: LDS accumulate (SoA) + layer-1 epilogue, Td2 = (h1@W2)*dinv.
__global__ __launch_bounds__(256) void agg1_kernel(const int* __restrict__ curR, const int* __restrict__ pairs,
                                                   const float* __restrict__ dinv, const float4* __restrict__ Td1,
                                                   float4* __restrict__ Bv, const float* __restrict__ b1,
                                                   const float* __restrict__ W2, float4* __restrict__ Td2, int n) {
    __shared__ float acc[4 * 256];
    const int b = blockIdx.x, t = threadIdx.x;
    acc[t] = 0.f; acc[256 + t] = 0.f; acc[512 + t] = 0.f; acc[768 + t] = 0.f;
    __syncthreads();
    int base = b * CAPB;
    int cnt = curR[b] - base; if (cnt > CAPB) cnt = CAPB;
    for (int k = t; k < cnt; k += 256) {
        int p = pairs[base + k];
        int c = p & 0xFFFFFF;
        int rl = ((unsigned)p) >> 24;
        float4 tv = Td1[c];
        atomicAdd(&acc[rl],       tv.x);
        atomicAdd(&acc[256 + rl], tv.y);
        atomicAdd(&acc[512 + rl], tv.z);
        atomicAdd(&acc[768 + rl], tv.w);
    }
    __syncthreads();
    int v = b * 256 + t;
    if (v >= n) return;
    float4 ob = Bv[v];
    float4 t0 = Td1[v];                              // self-loop
    float sx = acc[t]       + ob.x + t0.x;
    float sy = acc[256 + t] + ob.y + t0.y;
    float sz = acc[512 + t] + ob.z + t0.z;
    float sw = acc[768 + t] + ob.w + t0.w;
    float d = dinv[v];
    float h0 = tanhf(d * sx + b1[0]);
    float h1 = tanhf(d * sy + b1[1]);
    float h2 = tanhf(d * sz + b1[2]);
    float h3 = tanhf(d * sw + b1[3]);
    float4 o;
    o.x = (h0 * W2[0] + h1 * W2[4] + h2 * W2[8]  + h3 * W2[12]) * d;
    o.y = (h0 * W2[1] + h1 * W2[5] + h2 * W2[9]  + h3 * W2[13]) * d;
    o.z = (h0 * W2[2] + h1 * W2[6] + h2 * W2[10] + h3 * W2[14]) * d;
    o.w = (h0 * W2[3] + h1 * W2[7] + h2 * W2[11] + h3 * W2[15]) * d;
    Td2[v] = o;
    Bv[v] = make_float4(0.f, 0.f, 0.f, 0.f);         // reset for layer-2 overflow
}

// agg pass 2: -> Td3 = (h2@W3)*dinv  (4 -> 2).
__global__ __launch_bounds__(256) void agg2_kernel(const int* __restrict__ curR, const int* __restrict__ pairs,
                                                   const float* __restrict__ dinv, const float4* __restrict__ Td2,
                                                   const float4* __restrict__ Bv, const float* __restrict__ b2,
                                                   const float* __restrict__ W3, float2* __restrict__ Td3, int n) {
    __shared__ float acc[4 * 256];
    const int b = blockIdx.x, t = threadIdx.x;
    acc[t] = 0.f; acc[256 + t] = 0.f; acc[512 + t] = 0.f; acc[768 + t] = 0.f;
    __syncthreads();
    int base = b * CAPB;
    int cnt = curR[b] - base; if (cnt > CAPB) cnt = CAPB;
    for (int k = t; k < cnt; k += 256) {
        int p = pairs[base + k];
        int c = p & 0xFFFFFF;
        int rl = ((unsigned)p) >> 24;
        float4 tv = Td2[c];
        atomicAdd(&acc[rl],       tv.x);
        atomicAdd(&acc[256 + rl], tv.y);
        atomicAdd(&acc[512 + rl], tv.z);
        atomicAdd(&acc[768 + rl], tv.w);
    }
    __syncthreads();
    int v = b * 256 + t;
    if (v >= n) return;
    float4 ob = Bv[v];
    float4 t0 = Td2[v];
    float sx = acc[t]       + ob.x + t0.x;
    float sy = acc[256 + t] + ob.y + t0.y;
    float sz = acc[512 + t] + ob.z + t0.z;
    float sw = acc[768 + t] + ob.w + t0.w;
    float d = dinv[v];
    float h0 = tanhf(d * sx + b2[0]);
    float h1 = tanhf(d * sy + b2[1]);
    float h2 = tanhf(d * sz + b2[2]);
    float h3 = tanhf(d * sw + b2[3]);
    float2 o;
    o.x = (h0 * W3[0] + h1 * W3[2] + h2 * W3[4] + h3 * W3[6]) * d;
    o.y = (h0 * W3[1] + h1 * W3[3] + h2 * W3[5] + h3 * W3[7]) * d;
    Td3[v] = o;
}

// agg pass 3 + classifier: writes out [n,4] and h3 [n,2].
__global__ __launch_bounds__(256) void agg3_kernel(const int* __restrict__ curR, const int* __restrict__ pairs,
                                                   const float* __restrict__ dinv, const float2* __restrict__ Td3,
                                                   const float2* __restrict__ Dv, const float* __restrict__ b3,
                                                   const float* __restrict__ Wc, const float* __restrict__ bc,
                                                   float* __restrict__ out, int n) {
    __shared__ float acc[2 * 256];
    const int b = blockIdx.x, t = threadIdx.x;
    acc[t] = 0.f; acc[256 + t] = 0.f;
    __syncthreads();
    int base = b * CAPB;
    int cnt = curR[b] - base; if (cnt > CAPB) cnt = CAPB;
    for (int k = t; k < cnt; k += 256) {
        int p = pairs[base + k];
        int c = p & 0xFFFFFF;
        int rl = ((unsigned)p) >> 24;
        float2 tv = Td3[c];
        atomicAdd(&acc[rl],       tv.x);
        atomicAdd(&acc[256 + rl], tv.y);
    }
    __syncthreads();
    int v = b * 256 + t;
    if (v >= n) return;
    float2 ob = Dv[v];
    float2 t0 = Td3[v];
    float sx = acc[t]       + ob.x + t0.x;
    float sy = acc[256 + t] + ob.y + t0.y;
    float d = dinv[v];
    float h0 = tanhf(d * sx + b3[0]);
    float h1 = tanhf(d * sy + b3[1]);
    float4 o;
    o.x = h0 * Wc[0] + h1 * Wc[4] + bc[0];
    o.y = h0 * Wc[1] + h1 * Wc[5] + bc[1];
    o.z = h0 * Wc[2] + h1 * Wc[6] + bc[2];
    o.w = h0 * Wc[3] + h1 * Wc[7] + bc[3];
    ((float4*)out)[v] = o;
    ((float2*)(out + (size_t)n * 4))[v] = make_float2(h0, h1);
}

// ---------------- fallback path (round-2, proven 521us) ----------------

#define ELL_C 64

__global__ __launch_bounds__(256) void zero_kernel(int* __restrict__ p, long count) {
    long i = (long)blockIdx.x * blockDim.x + threadIdx.x;
    if (i < count) p[i] = 0;
}
__global__ __launch_bounds__(256) void build_kernel(const int* __restrict__ row, const int* __restrict__ col,
                                                    int* __restrict__ deg, int* __restrict__ cnt,
                                                    int* __restrict__ slots, int* __restrict__ ovfc,
                                                    int2* __restrict__ ovf, int n, int E) {
    int e = blockIdx.x * blockDim.x + threadIdx.x;
    if (e >= E) return;
    int r = row[e], c = col[e];
    atomicAdd(&deg[c], 1);
    int pos = atomicAdd(&cnt[r], 1);
    if (pos < ELL_C) {
        slots[(size_t)pos * n + r] = c;
    } else {
        int i = atomicAdd(ovfc, 1);
        if (i < OVF_CAP) ovf[i] = make_int2(r, c);
    }
}
__global__ __launch_bounds__(256) void dinv2_kernel(const int* __restrict__ deg, float* __restrict__ dinv, int n) {
    int v = blockIdx.x * blockDim.x + threadIdx.x;
    if (v >= n) return;
    dinv[v] = rsqrtf((float)(deg[v] + 1));
}
__global__ __launch_bounds__(256) void agg_node1(const int* __restrict__ cnt, const int* __restrict__ slots,
                                                 const float* __restrict__ dinv, const float4* __restrict__ Td1,
                                                 float4* __restrict__ B, const float* __restrict__ b1,
                                                 const float* __restrict__ W2, float4* __restrict__ Td2, int n) {
    int v = blockIdx.x * blockDim.x + threadIdx.x;
    if (v >= n) return;
    int k = cnt[v]; if (k > ELL_C) k = ELL_C;
    float4 s = B[v];
    for (int j = 0; j < k; ++j) {
        int c = slots[(size_t)j * n + v];
        float4 t = Td1[c];
        s.x += t.x; s.y += t.y; s.z += t.z; s.w += t.w;
    }
    float4 t0 = Td1[v];
    s.x += t0.x; s.y += t0.y; s.z += t0.z; s.w += t0.w;
    float d = dinv[v];
    float h0 = tanhf(d * s.x + b1[0]);
    float h1 = tanhf(d * s.y + b1[1]);
    float h2 = tanhf(d * s.z + b1[2]);
    float h3 = tanhf(d * s.w + b1[3]);
    float4 o;
    o.x = (h0 * W2[0] + h1 * W2[4] + h2 * W2[8]  + h3 * W2[12]) * d;
    o.y = (h0 * W2[1] + h1 * W2[5] + h2 * W2[9]  + h3 * W2[13]) * d;
    o.z = (h0 * W2[2] + h1 * W2[6] + h2 * W2[10] + h3 * W2[14]) * d;
    o.w = (h0 * W2[3] + h1 * W2[7] + h2 * W2[11] + h3 * W2[15]) * d;
    Td2[v] = o;
    B[v] = make_float4(0.f, 0.f, 0.f, 0.f);
}
__global__ __launch_bounds__(256) void agg_node2(const int* __restrict__ cnt, const int* __restrict__ slots,
                                                 const float* __restrict__ dinv, const float4* __restrict__ Td2,
                                                 const float4* __restrict__ B, const float* __restrict__ b2,
                                                 const float* __restrict__ W3, float2* __restrict__ Td3, int n) {
    int v = blockIdx.x * blockDim.x + threadIdx.x;
    if (v >= n) return;
    int k = cnt[v]; if (k > ELL_C) k = ELL_C;
    float4 s = B[v];
    for (int j = 0; j < k; ++j) {
        int c = slots[(size_t)j * n + v];
        float4 t = Td2[c];
        s.x += t.x; s.y += t.y; s.z += t.z; s.w += t.w;
    }
    float4 t0 = Td2[v];
    s.x += t0.x; s.y += t0.y; s.z += t0.z; s.w += t0.w;
    float d = dinv[v];
    float h0 = tanhf(d * s.x + b2[0]);
    float h1 = tanhf(d * s.y + b2[1]);
    float h2 = tanhf(d * s.z + b2[2]);
    float h3 = tanhf(d * s.w + b2[3]);
    float2 o;
    o.x = (h0 * W3[0] + h1 * W3[2] + h2 * W3[4] + h3 * W3[6]) * d;
    o.y = (h0 * W3[1] + h1 * W3[3] + h2 * W3[5] + h3 * W3[7]) * d;
    Td3[v] = o;
}
__global__ __launch_bounds__(256) void agg_node3(const int* __restrict__ cnt, const int* __restrict__ slots,
                                                 const float* __restrict__ dinv, const float2* __restrict__ Td3,
                                                 const float2* __restrict__ D, const float* __restrict__ b3,
                                                 const float* __restrict__ Wc, const float* __restrict__ bc,
                                                 float* __restrict__ out, int n) {
    int v = blockIdx.x * blockDim.x + threadIdx.x;
    if (v >= n) return;
    int k = cnt[v]; if (k > ELL_C) k = ELL_C;
    float2 s = D[v];
    for (int j = 0; j < k; ++j) {
        int c = slots[(size_t)j * n + v];
        float2 t = Td3[c];
        s.x += t.x; s.y += t.y;
    }
    float2 t0 = Td3[v];
    s.x += t0.x; s.y += t0.y;
    float d = dinv[v];
    float h0 = tanhf(d * s.x + b3[0]);
    float h1 = tanhf(d * s.y + b3[1]);
    float4 o;
    o.x = h0 * Wc[0] + h1 * Wc[4] + bc[0];
    o.y = h0 * Wc[1] + h1 * Wc[5] + bc[1];
    o.z = h0 * Wc[2] + h1 * Wc[6] + bc[2];
    o.w = h0 * Wc[3] + h1 * Wc[7] + bc[3];
    ((float4*)out)[v] = o;
    ((float2*)(out + (size_t)n * 4))[v] = make_float2(h0, h1);
}

extern "C" void kernel_launch(void* const* d_in, const int* in_sizes, int n_in,
                              void* d_out, int out_size, void* d_ws, size_t ws_size,
                              hipStream_t stream) {
    const float* x  = (const float*)d_in[0];
    const int*   ei = (const int*)  d_in[1];
    const float* W1 = (const float*)d_in[2];
    const float* b1 = (const float*)d_in[3];
    const float* W2 = (const float*)d_in[4];
    const float* b2 = (const float*)d_in[5];
    const float* W3 = (const float*)d_in[6];
    const float* b3 = (const float*)d_in[7];
    const float* Wc = (const float*)d_in[8];
    const float* bc = (const float*)d_in[9];

    const size_t n = (size_t)(in_sizes[0] / 128);
    const int    E = in_sizes[1] / 2;
    const int* row = ei;       // destinations (segment ids)
    const int* col = ei + E;   // sources (gather)

    const int B     = (int)((n + 255) >> 8);
    const int nb_n  = (int)((n + 255) / 256);
    const int nb_e  = (E + 255) / 256;
    const int nb_mm = (int)((n * 64 + 255) / 256);
    const int nb_ov = OVF_CAP / 256;
    const int nb_p  = (E + CHUNK - 1) / CHUNK;

    int* ws = (int*)d_ws;

    // fast-path layout (ints): pairs B*CAPB | union max(B*CAPB,16n) | dinv n |
    // deg n | curR B | curC B | ovfRc 1 | ovfCc 1 | ovfR 2*OVF_CAP | ovfC OVF_CAP
    size_t uni  = (size_t)B * CAPB; if (uni < 16 * n) uni = 16 * n;
    size_t need_fast = ((size_t)B * CAPB + uni + 2 * n + 2 * (size_t)B + 2 + 3 * OVF_CAP) * 4 + 64;

    if (ws_size >= need_fast && n <= (1u << 24) && B <= NBMAX) {
        int*   pairs = ws;
        int*   bufU  = pairs + (size_t)B * CAPB;       // union: bufC then Td1/Td2/Td3/Bv/Dv
        float* Td1   = (float*)bufU;                   // 4n
        float* Td2   = Td1 + 4 * n;                    // 4n
        float* Td3   = Td2 + 4 * n;                    // 2n
        float* Bv    = Td3 + 2 * n;                    // 4n
        float* Dv    = Bv + 4 * n;                     // 2n
        int*   bufC  = bufU;                           // aliases Td region (dead after histo)
        float* dinv  = (float*)(bufU + uni);           // n
        int*   deg   = (int*)(dinv + n);               // n
        int*   curR  = deg + n;                        // B
        int*   curC  = curR + B;                       // B
        int*   ovfRc = curC + B;                       // 1
        int*   ovfCc = ovfRc + 1;                      // 1
        int2*  ovfR  = (int2*)(ovfCc + 1);             // align: offset is even? force it:
        {   // ensure 8B alignment for int2
            size_t off = (size_t)(ovfCc + 1 - ws);
            if (off & 1) ovfR = (int2*)(ovfCc + 2);
        }
        int*   ovfC  = (int*)(ovfR + OVF_CAP);

        initc_kernel<<<(B + 255) / 256, 256, 0, stream>>>(curR, curC, ovfRc, ovfCc, B);
        part_kernel<<<nb_p, 256, 0, stream>>>(row, col, curR, curC, pairs, bufC,
                                              ovfRc, ovfR, ovfCc, ovfC, B, E);
        histo_kernel<<<B, 256, 0, stream>>>(curC, bufC, deg, (int)n);
        ovfc_deg_kernel<<<nb_ov, 256, 0, stream>>>(ovfCc, ovfC, deg);
        dinvz_kernel<<<nb_n, 256, 0, stream>>>(deg, dinv, (float4*)Bv, (float2*)Dv, (int)n);
        // bufC dead from here; Td region live.
        mm1_kernel<<<nb_mm, 256, 0, stream>>>(x, W1, dinv, (float4*)Td1, (int)n);

        ovf4_kernel<<<nb_ov, 256, 0, stream>>>(ovfRc, ovfR, (const float4*)Td1, Bv);
        agg1_kernel<<<B, 256, 0, stream>>>(curR, pairs, dinv, (const float4*)Td1, (float4*)Bv,
                                           b1, W2, (float4*)Td2, (int)n);

        ovf4_kernel<<<nb_ov, 256, 0, stream>>>(ovfRc, ovfR, (const float4*)Td2, Bv);
        agg2_kernel<<<B, 256, 0, stream>>>(curR, pairs, dinv, (const float4*)Td2, (const float4*)Bv,
                                           b2, W3, (float2*)Td3, (int)n);

        ovf2_kernel<<<nb_ov, 256, 0, stream>>>(ovfRc, ovfR, (const float2*)Td3, Dv);
        agg3_kernel<<<B, 256, 0, stream>>>(curR, pairs, dinv, (const float2*)Td3, (const float2*)Dv,
                                           b3, Wc, bc, (float*)d_out, (int)n);
    } else {
        // fallback: round-2 ELL path (proven)
        float* fws  = (float*)d_ws;
        float* A1   = fws;
        float* A2   = A1 + 4 * n;
        float* C3   = A2 + 4 * n;
        float* Bv   = C3 + 2 * n;
        float* Dv   = Bv + 4 * n;
        float* dinv = Dv + 2 * n;
        int*   cnt  = (int*)(dinv + n);
        int*   deg  = cnt + n;
        int*   ovfc = deg + n;
        int2*  ovf  = (int2*)(ovfc + 4);
        int*   slots = (int*)(ovf + OVF_CAP);

        long zc = (long)(9 * n + 4);
        zero_kernel<<<(int)((zc + 255) / 256), 256, 0, stream>>>((int*)Bv, zc);
        build_kernel<<<nb_e, 256, 0, stream>>>(row, col, deg, cnt, slots, ovfc, ovf, (int)n, E);
        dinv2_kernel<<<nb_n, 256, 0, stream>>>(deg, dinv, (int)n);
        mm1_kernel<<<nb_mm, 256, 0, stream>>>(x, W1, dinv, (float4*)A1, (int)n);
        ovf4_kernel<<<nb_ov, 256, 0, stream>>>(ovfc, ovf, (const float4*)A1, Bv);
        agg_node1<<<nb_n, 256, 0, stream>>>(cnt, slots, dinv, (const float4*)A1, (float4*)Bv, b1, W2, (float4*)A2, (int)n);
        ovf4_kernel<<<nb_ov, 256, 0, stream>>>(ovfc, ovf, (const float4*)A2, Bv);
        agg_node2<<<nb_n, 256, 0, stream>>>(cnt, slots, dinv, (const float4*)A2, (const float4*)Bv, b2, W3, (float2*)C3, (int)n);
        ovf2_kernel<<<nb_ov, 256, 0, stream>>>(ovfc, ovf, (const float2*)C3, Dv);
        agg_node3<<<nb_n, 256, 0, stream>>>(cnt, slots, dinv, (const float2*)C3, (const float2*)Dv, b3, Wc, bc, (float*)d_out, (int)n);
    }
}

// Round 5
// 440.905 us; speedup vs baseline: 1.6551x; 1.0088x over previous
//
#include <hip/hip_runtime.h>
#include <math.h>

// GCN: h = D^-1/2 (A+I) D^-1/2 (x W) + b, 3 layers + classifier.
// N = 100000 nodes, E = 3.2M edges, feats 128 -> 4 -> 4 -> 2 -> 4.
//
// Round 5: round-4 agg kernels were latency-bound at 391 blocks (12% occ,
// VALU 0.85%, HBM 2.4%): 64-line divergent Td gathers with ~6 waves/CU to
// overlap them. Fix = split each bucket across 8 sub-blocks (grid 3128),
// LDS partials -> coalesced partial dump -> node-parallel merge+epilogue.
// part_kernel: CHUNK 8192->4096 for 2x blocks (writes were interleave-broken
// regardless of run length).

#define OVF_CAP 32768
#define NBMAX   512      // max buckets (n <= 131072)
#define CHUNK   4096     // edges per partition block
#define CAPB    11776    // bucket capacity (expected 8192 uniform; 1.44x)
#define SPLIT   8        // agg sub-blocks per bucket

// ---------------- shared kernels ----------------

// x [n,128] @ W1 [128,4] -> Td1 [n,4], pre-scaled by dinv[v].
__global__ __launch_bounds__(256) void mm1_kernel(const float* __restrict__ x, const float* __restrict__ W1,
                                                  const float* __restrict__ dinv, float4* __restrict__ Td1, int n) {
    int gid  = blockIdx.x * blockDim.x + threadIdx.x;
    int lane = threadIdx.x & 63;
    int v    = gid >> 6;
    if (v >= n) return;
    float2 xv = ((const float2*)x)[(size_t)v * 64 + lane];
    float4 wa = ((const float4*)W1)[2 * lane];
    float4 wb = ((const float4*)W1)[2 * lane + 1];
    float p0 = xv.x * wa.x + xv.y * wb.x;
    float p1 = xv.x * wa.y + xv.y * wb.y;
    float p2 = xv.x * wa.z + xv.y * wb.z;
    float p3 = xv.x * wa.w + xv.y * wb.w;
#pragma unroll
    for (int off = 32; off > 0; off >>= 1) {
        p0 += __shfl_xor(p0, off);
        p1 += __shfl_xor(p1, off);
        p2 += __shfl_xor(p2, off);
        p3 += __shfl_xor(p3, off);
    }
    if (lane == 0) {
        float d = dinv[v];
        Td1[v] = make_float4(p0 * d, p1 * d, p2 * d, p3 * d);
    }
}

__global__ __launch_bounds__(256) void ovf4_kernel(const int* __restrict__ ovfc, const int2* __restrict__ ovf,
                                                   const float4* __restrict__ Td, float* __restrict__ B) {
    int e = blockIdx.x * blockDim.x + threadIdx.x;
    int m = *ovfc; if (m > OVF_CAP) m = OVF_CAP;
    if (e >= m) return;
    int2 rc = ovf[e];
    float4 t = Td[rc.y];
    atomicAdd(&B[rc.x * 4 + 0], t.x);
    atomicAdd(&B[rc.x * 4 + 1], t.y);
    atomicAdd(&B[rc.x * 4 + 2], t.z);
    atomicAdd(&B[rc.x * 4 + 3], t.w);
}

__global__ __launch_bounds__(256) void ovf2_kernel(const int* __restrict__ ovfc, const int2* __restrict__ ovf,
                                                   const float2* __restrict__ Td, float* __restrict__ D) {
    int e = blockIdx.x * blockDim.x + threadIdx.x;
    int m = *ovfc; if (m > OVF_CAP) m = OVF_CAP;
    if (e >= m) return;
    int2 rc = ovf[e];
    float2 t = Td[rc.y];
    atomicAdd(&D[rc.x * 2 + 0], t.x);
    atomicAdd(&D[rc.x * 2 + 1], t.y);
}

// ---------------- fast path: bucket partition build ----------------

__global__ __launch_bounds__(256) void initc_kernel(int* __restrict__ curR, int* __restrict__ curC,
                                                    int* __restrict__ ovfRc, int* __restrict__ ovfCc, int B) {
    int i = blockIdx.x * blockDim.x + threadIdx.x;
    if (i == 0) { *ovfRc = 0; *ovfCc = 0; }
    if (i < B) { curR[i] = i * CAPB; curC[i] = i * CAPB; }
}

// Bin edges by r>>8 into pairs[] (packed r_local<<24|c) and by c>>8 into bufC[].
__global__ __launch_bounds__(256) void part_kernel(const int* __restrict__ row, const int* __restrict__ col,
                                                   int* __restrict__ curR, int* __restrict__ curC,
                                                   int* __restrict__ pairs, int* __restrict__ bufC,
                                                   int* __restrict__ ovfRc, int2* __restrict__ ovfR,
                                                   int* __restrict__ ovfCc, int* __restrict__ ovfC,
                                                   int B, int E) {
    __shared__ int hR[NBMAX], hC[NBMAX], bR[NBMAX], bC[NBMAX];
    const int t = threadIdx.x;
    const long e0 = (long)blockIdx.x * CHUNK;
    for (int i = t; i < B; i += 256) { hR[i] = 0; hC[i] = 0; }
    __syncthreads();
#pragma unroll 4
    for (int k = 0; k < CHUNK / 256; ++k) {
        long e = e0 + (long)k * 256 + t;
        if (e < E) {
            atomicAdd(&hR[row[e] >> 8], 1);
            atomicAdd(&hC[col[e] >> 8], 1);
        }
    }
    __syncthreads();
    for (int i = t; i < B; i += 256) {
        int nr = hR[i];
        bR[i] = nr ? atomicAdd(&curR[i], nr) : 0;
        hR[i] = 0;
        int nc = hC[i];
        bC[i] = nc ? atomicAdd(&curC[i], nc) : 0;
        hC[i] = 0;
    }
    __syncthreads();
#pragma unroll 4
    for (int k = 0; k < CHUNK / 256; ++k) {
        long e = e0 + (long)k * 256 + t;
        if (e < E) {
            int r = row[e], c = col[e];
            int b = r >> 8;
            int pos = bR[b] + atomicAdd(&hR[b], 1);
            if (pos < (b + 1) * CAPB) {
                pairs[pos] = ((r & 255) << 24) | c;
            } else {
                int i = atomicAdd(ovfRc, 1);
                if (i < OVF_CAP) ovfR[i] = make_int2(r, c);
            }
            int bc2 = c >> 8;
            int posc = bC[bc2] + atomicAdd(&hC[bc2], 1);
            if (posc < (bc2 + 1) * CAPB) {
                bufC[posc] = c;
            } else {
                int i = atomicAdd(ovfCc, 1);
                if (i < OVF_CAP) ovfC[i] = c;
            }
        }
    }
}

// deg from source-binned copy: per-bucket LDS histogram, sequential write.
__global__ __launch_bounds__(256) void histo_kernel(const int* __restrict__ curC, const int* __restrict__ bufC,
                                                    int* __restrict__ deg, int n) {
    __shared__ int h[256];
    const int b = blockIdx.x, t = threadIdx.x;
    h[t] = 0;
    __syncthreads();
    int base = b * CAPB;
    int cnt = curC[b] - base; if (cnt > CAPB) cnt = CAPB;
    for (int k = t; k < cnt; k += 256) atomicAdd(&h[bufC[base + k] & 255], 1);
    __syncthreads();
    int v = b * 256 + t;
    if (v < n) deg[v] = h[t];
}

__global__ __launch_bounds__(256) void ovfc_deg_kernel(const int* __restrict__ ovfCc, const int* __restrict__ ovfC,
                                                       int* __restrict__ deg) {
    int i = blockIdx.x * blockDim.x + threadIdx.x;
    int m = *ovfCc; if (m > OVF_CAP) m = OVF_CAP;
    if (i >= m) return;
    atomicAdd(&deg[ovfC[i]], 1);
}

__global__ __launch_bounds__(256) void dinvz_kernel(const int* __restrict__ deg, float* __restrict__ dinv,
                                                    float4* __restrict__ Bv, float2* __restrict__ Dv, int n) {
    int v = blockIdx.x * blockDim.x + threadIdx.x;
    if (v >= n) return;
    dinv[v] = rsqrtf((float)(deg[v] + 1));
    Bv[v] = make_float4(0.f, 0.f, 0.f, 0.f);
    Dv[v] = make_float2(0.f, 0.f);
}

// agg partial pass, 4-feat: sub-block (b,s) accumulates its slice of bucket b
// into LDS, dumps dense partial (coalesced). grid = B*SPLIT.
__global__ __launch_bounds__(256) void aggp4_kernel(const int* __restrict__ curR, const int* __restrict__ pairs,
                                                    const float4* __restrict__ Td, float* __restrict__ P) {
    __shared__ float acc[1024];
    const int t = threadIdx.x;
    const int b = blockIdx.x >> 3, s = blockIdx.x & 7;
    acc[t] = 0.f; acc[256 + t] = 0.f; acc[512 + t] = 0.f; acc[768 + t] = 0.f;
    __syncthreads();
    int base = b * CAPB;
    int cnt = curR[b] - base; if (cnt > CAPB) cnt = CAPB; if (cnt < 0) cnt = 0;
    int lo = base + (int)(((long)cnt * s) >> 3);
    int hi = base + (int)(((long)cnt * (s + 1)) >> 3);
    for (int k = lo + t; k < hi; k += 256) {
        int p = pairs[k];
        int c = p & 0xFFFFFF;
        int rl = ((unsigned)p) >> 24;
        float4 tv = Td[c];
        atomicAdd(&acc[rl],       tv.x);
        atomicAdd(&acc[256 + rl], tv.y);
        atomicAdd(&acc[512 + rl], tv.z);
        atomicAdd(&acc[768 + rl], tv.w);
    }
    __syncthreads();
    float* Pb = P + ((size_t)blockIdx.x << 10);
    Pb[t] = acc[t]; Pb[256 + t] = acc[256 + t]; Pb[512 + t] = acc[512 + t]; Pb[768 + t] = acc[768 + t];
}

// 2-feat variant for layer 3.
__global__ __launch_bounds__(256) void aggp2_kernel(const int* __restrict__ curR, const int* __restrict__ pairs,
                                                    const float2* __restrict__ Td, float* __restrict__ P) {
    __shared__ float acc[512];
    const int t = threadIdx.x;
    const int b = blockIdx.x >> 3, s = blockIdx.x & 7;
    acc[t] = 0.f; acc[256 + t] = 0.f;
    __syncthreads();
    int base = b * CAPB;
    int cnt = curR[b] - base; if (cnt > CAPB) cnt = CAPB; if (cnt < 0) cnt = 0;
    int lo = base + (int)(((long)cnt * s) >> 3);
    int hi = base + (int)(((long)cnt * (s + 1)) >> 3);
    for (int k = lo + t; k < hi; k += 256) {
        int p = pairs[k];
        int c = p & 0xFFFFFF;
        int rl = ((unsigned)p) >> 24;
        float2 tv = Td[c];
        atomicAdd(&acc[rl],       tv.x);
        atomicAdd(&acc[256 + rl], tv.y);
    }
    __syncthreads();
    float* Pb = P + ((size_t)blockIdx.x << 9);
    Pb[t] = acc[t]; Pb[256 + t] = acc[256 + t];
}

// merge 8 partials + layer-1 epilogue: h1 = tanh(dinv*(sum+self)+b1), Td2=(h1@W2)*dinv.
__global__ __launch_bounds__(256) void merge1_kernel(const float* __restrict__ P, const float* __restrict__ dinv,
                                                     const float4* __restrict__ Td1, float4* __restrict__ Bv,
                                                     const float* __restrict__ b1, const float* __restrict__ W2,
                                                     float4* __restrict__ Td2, int n) {
    const int t = threadIdx.x;
    const int v = blockIdx.x * 256 + t;
    if (v >= n) return;
    const float* Pb = P + ((size_t)blockIdx.x << 13);
    float sx = 0.f, sy = 0.f, sz = 0.f, sw = 0.f;
#pragma unroll
    for (int s = 0; s < SPLIT; ++s) {
        sx += Pb[s * 1024 + t];
        sy += Pb[s * 1024 + 256 + t];
        sz += Pb[s * 1024 + 512 + t];
        sw += Pb[s * 1024 + 768 + t];
    }
    float4 ob = Bv[v];
    float4 t0 = Td1[v];                              // self-loop
    sx += ob.x + t0.x; sy += ob.y + t0.y; sz += ob.z + t0.z; sw += ob.w + t0.w;
    float d = dinv[v];
    float h0 = tanhf(d * sx + b1[0]);
    float h1 = tanhf(d * sy + b1[1]);
    float h2 = tanhf(d * sz + b1[2]);
    float h3 = tanhf(d * sw + b1[3]);
    float4 o;
    o.x = (h0 * W2[0] + h1 * W2[4] + h2 * W2[8]  + h3 * W2[12]) * d;
    o.y = (h0 * W2[1] + h1 * W2[5] + h2 * W2[9]  + h3 * W2[13]) * d;
    o.z = (h0 * W2[2] + h1 * W2[6] + h2 * W2[10] + h3 * W2[14]) * d;
    o.w = (h0 * W2[3] + h1 * W2[7] + h2 * W2[11] + h3 * W2[15]) * d;
    Td2[v] = o;
    Bv[v] = make_float4(0.f, 0.f, 0.f, 0.f);         // reset for layer-2 overflow
}

__global__ __launch_bounds__(256) void merge2_kernel(const float* __restrict__ P, const float* __restrict__ dinv,
                                                     const float4* __restrict__ Td2, const float4* __restrict__ Bv,
                                                     const float* __restrict__ b2, const float* __restrict__ W3,
                                                     float2* __restrict__ Td3, int n) {
    const int t = threadIdx.x;
    const int v = blockIdx.x * 256 + t;
    if (v >= n) return;
    const float* Pb = P + ((size_t)blockIdx.x << 13);
    float sx = 0.f, sy = 0.f, sz = 0.f, sw = 0.f;
#pragma unroll
    for (int s = 0; s < SPLIT; ++s) {
        sx += Pb[s * 1024 + t];
        sy += Pb[s * 1024 + 256 + t];
        sz += Pb[s * 1024 + 512 + t];
        sw += Pb[s * 1024 + 768 + t];
    }
    float4 ob = Bv[v];
    float4 t0 = Td2[v];
    sx += ob.x + t0.x; sy += ob.y + t0.y; sz += ob.z + t0.z; sw += ob.w + t0.w;
    float d = dinv[v];
    float h0 = tanhf(d * sx + b2[0]);
    float h1 = tanhf(d * sy + b2[1]);
    float h2 = tanhf(d * sz + b2[2]);
    float h3 = tanhf(d * sw + b2[3]);
    float2 o;
    o.x = (h0 * W3[0] + h1 * W3[2] + h2 * W3[4] + h3 * W3[6]) * d;
    o.y = (h0 * W3[1] + h1 * W3[3] + h2 * W3[5] + h3 * W3[7]) * d;
    Td3[v] = o;
}

__global__ __launch_bounds__(256) void merge3_kernel(const float* __restrict__ P, const float* __restrict__ dinv,
                                                     const float2* __restrict__ Td3, const float2* __restrict__ Dv,
                                                     const float* __restrict__ b3, const float* __restrict__ Wc,
                                                     const float* __restrict__ bc, float* __restrict__ out, int n) {
    const int t = threadIdx.x;
    const int v = blockIdx.x * 256 + t;
    if (v >= n) return;
    const float* Pb = P + ((size_t)blockIdx.x << 12);
    float sx = 0.f, sy = 0.f;
#pragma unroll
    for (int s = 0; s < SPLIT; ++s) {
        sx += Pb[s * 512 + t];
        sy += Pb[s * 512 + 256 + t];
    }
    float2 ob = Dv[v];
    float2 t0 = Td3[v];
    sx += ob.x + t0.x; sy += ob.y + t0.y;
    float d = dinv[v];
    float h0 = tanhf(d * sx + b3[0]);
    float h1 = tanhf(d * sy + b3[1]);
    float4 o;
    o.x = h0 * Wc[0] + h1 * Wc[4] + bc[0];
    o.y = h0 * Wc[1] + h1 * Wc[5] + bc[1];
    o.z = h0 * Wc[2] + h1 * Wc[6] + bc[2];
    o.w = h0 * Wc[3] + h1 * Wc[7] + bc[3];
    ((float4*)out)[v] = o;
    ((float2*)(out + (size_t)n * 4))[v] = make_float2(h0, h1);
}

// ---------------- fallback path (round-2, proven) ----------------

#define ELL_C 64

__global__ __launch_bounds__(256) void zero_kernel(int* __restrict__ p, long count) {
    long i = (long)blockIdx.x * blockDim.x + threadIdx.x;
    if (i < count) p[i] = 0;
}
__global__ __launch_bounds__(256) void build_kernel(const int* __restrict__ row, const int* __restrict__ col,
                                                    int* __restrict__ deg, int* __restrict__ cnt,
                                                    int* __restrict__ slots, int* __restrict__ ovfc,
                                                    int2* __restrict__ ovf, int n, int E) {
    int e = blockIdx.x * blockDim.x + threadIdx.x;
    if (e >= E) return;
    int r = row[e], c = col[e];
    atomicAdd(&deg[c], 1);
    int pos = atomicAdd(&cnt[r], 1);
    if (pos < ELL_C) {
        slots[(size_t)pos * n + r] = c;
    } else {
        int i = atomicAdd(ovfc, 1);
        if (i < OVF_CAP) ovf[i] = make_int2(r, c);
    }
}
__global__ __launch_bounds__(256) void dinv2_kernel(const int* __restrict__ deg, float* __restrict__ dinv, int n) {
    int v = blockIdx.x * blockDim.x + threadIdx.x;
    if (v >= n) return;
    dinv[v] = rsqrtf((float)(deg[v] + 1));
}
__global__ __launch_bounds__(256) void agg_node1(const int* __restrict__ cnt, const int* __restrict__ slots,
                                                 const float* __restrict__ dinv, const float4* __restrict__ Td1,
                                                 float4* __restrict__ B, const float* __restrict__ b1,
                                                 const float* __restrict__ W2, float4* __restrict__ Td2, int n) {
    int v = blockIdx.x * blockDim.x + threadIdx.x;
    if (v >= n) return;
    int k = cnt[v]; if (k > ELL_C) k = ELL_C;
    float4 s = B[v];
    for (int j = 0; j < k; ++j) {
        int c = slots[(size_t)j * n + v];
        float4 t = Td1[c];
        s.x += t.x; s.y += t.y; s.z += t.z; s.w += t.w;
    }
    float4 t0 = Td1[v];
    s.x += t0.x; s.y += t0.y; s.z += t0.z; s.w += t0.w;
    float d = dinv[v];
    float h0 = tanhf(d * s.x + b1[0]);
    float h1 = tanhf(d * s.y + b1[1]);
    float h2 = tanhf(d * s.z + b1[2]);
    float h3 = tanhf(d * s.w + b1[3]);
    float4 o;
    o.x = (h0 * W2[0] + h1 * W2[4] + h2 * W2[8]  + h3 * W2[12]) * d;
    o.y = (h0 * W2[1] + h1 * W2[5] + h2 * W2[9]  + h3 * W2[13]) * d;
    o.z = (h0 * W2[2] + h1 * W2[6] + h2 * W2[10] + h3 * W2[14]) * d;
    o.w = (h0 * W2[3] + h1 * W2[7] + h2 * W2[11] + h3 * W2[15]) * d;
    Td2[v] = o;
    B[v] = make_float4(0.f, 0.f, 0.f, 0.f);
}
__global__ __launch_bounds__(256) void agg_node2(const int* __restrict__ cnt, const int* __restrict__ slots,
                                                 const float* __restrict__ dinv, const float4* __restrict__ Td2,
                                                 const float4* __restrict__ B, const float* __restrict__ b2,
                                                 const float* __restrict__ W3, float2* __restrict__ Td3, int n) {
    int v = blockIdx.x * blockDim.x + threadIdx.x;
    if (v >= n) return;
    int k = cnt[v]; if (k > ELL_C) k = ELL_C;
    float4 s = B[v];
    for (int j = 0; j < k; ++j) {
        int c = slots[(size_t)j * n + v];
        float4 t = Td2[c];
        s.x += t.x; s.y += t.y; s.z += t.z; s.w += t.w;
    }
    float4 t0 = Td2[v];
    s.x += t0.x; s.y += t0.y; s.z += t0.z; s.w += t0.w;
    float d = dinv[v];
    float h0 = tanhf(d * s.x + b2[0]);
    float h1 = tanhf(d * s.y + b2[1]);
    float h2 = tanhf(d * s.z + b2[2]);
    float h3 = tanhf(d * s.w + b2[3]);
    float2 o;
    o.x = (h0 * W3[0] + h1 * W3[2] + h2 * W3[4] + h3 * W3[6]) * d;
    o.y = (h0 * W3[1] + h1 * W3[3] + h2 * W3[5] + h3 * W3[7]) * d;
    Td3[v] = o;
}
__global__ __launch_bounds__(256) void agg_node3(const int* __restrict__ cnt, const int* __restrict__ slots,
                                                 const float* __restrict__ dinv, const float2* __restrict__ Td3,
                                                 const float2* __restrict__ D, const float* __restrict__ b3,
                                                 const float* __restrict__ Wc, const float* __restrict__ bc,
                                                 float* __restrict__ out, int n) {
    int v = blockIdx.x * blockDim.x + threadIdx.x;
    if (v >= n) return;
    int k = cnt[v]; if (k > ELL_C) k = ELL_C;
    float2 s = D[v];
    for (int j = 0; j < k; ++j) {
        int c = slots[(size_t)j * n + v];
        float2 t = Td3[c];
        s.x += t.x; s.y += t.y;
    }
    float2 t0 = Td3[v];
    s.x += t0.x; s.y += t0.y;
    float d = dinv[v];
    float h0 = tanhf(d * s.x + b3[0]);
    float h1 = tanhf(d * s.y + b3[1]);
    float4 o;
    o.x = h0 * Wc[0] + h1 * Wc[4] + bc[0];
    o.y = h0 * Wc[1] + h1 * Wc[5] + bc[1];
    o.z = h0 * Wc[2] + h1 * Wc[6] + bc[2];
    o.w = h0 * Wc[3] + h1 * Wc[7] + bc[3];
    ((float4*)out)[v] = o;
    ((float2*)(out + (size_t)n * 4))[v] = make_float2(h0, h1);
}

extern "C" void kernel_launch(void* const* d_in, const int* in_sizes, int n_in,
                              void* d_out, int out_size, void* d_ws, size_t ws_size,
                              hipStream_t stream) {
    const float* x  = (const float*)d_in[0];
    const int*   ei = (const int*)  d_in[1];
    const float* W1 = (const float*)d_in[2];
    const float* b1 = (const float*)d_in[3];
    const float* W2 = (const float*)d_in[4];
    const float* b2 = (const float*)d_in[5];
    const float* W3 = (const float*)d_in[6];
    const float* b3 = (const float*)d_in[7];
    const float* Wc = (const float*)d_in[8];
    const float* bc = (const float*)d_in[9];

    const size_t n = (size_t)(in_sizes[0] / 128);
    const int    E = in_sizes[1] / 2;
    const int* row = ei;       // destinations (segment ids)
    const int* col = ei + E;   // sources (gather)

    const int B     = (int)((n + 255) >> 8);
    const int nb_n  = (int)((n + 255) / 256);
    const int nb_e  = (E + 255) / 256;
    const int nb_mm = (int)((n * 64 + 255) / 256);
    const int nb_ov = OVF_CAP / 256;
    const int nb_p  = (E + CHUNK - 1) / CHUNK;

    int* ws = (int*)d_ws;

    // fast-path layout (ints): pairs B*CAPB | bufU uni | dinv n | deg n |
    // curR B | curC B | ovfRc 1 | ovfCc 1 | ovfR 2*OVF_CAP | ovfC OVF_CAP
    // bufU holds bufC (build) then Td1(4n) Td2(4n) Td3(2n) Bv(4n) Dv(2n) P(B*SPLIT*1024)
    size_t uni = (size_t)B * CAPB;
    size_t td_plus_p = 16 * n + (size_t)B * SPLIT * 1024;
    if (uni < td_plus_p) uni = td_plus_p;
    size_t need_fast = ((size_t)B * CAPB + uni + 2 * n + 2 * (size_t)B + 2 + 3 * OVF_CAP) * 4 + 64;

    if (ws_size >= need_fast && n <= (1u << 24) && B <= NBMAX) {
        int*   pairs = ws;
        int*   bufU  = pairs + (size_t)B * CAPB;
        float* Td1   = (float*)bufU;                   // 4n
        float* Td2   = Td1 + 4 * n;                    // 4n
        float* Td3   = Td2 + 4 * n;                    // 2n
        float* Bv    = Td3 + 2 * n;                    // 4n
        float* Dv    = Bv + 4 * n;                     // 2n
        float* P     = Dv + 2 * n;                     // B*SPLIT*1024 (aliases dead bufC tail)
        int*   bufC  = bufU;                           // dead after histo
        float* dinv  = (float*)(bufU + uni);           // n
        int*   deg   = (int*)(dinv + n);               // n
        int*   curR  = deg + n;                        // B
        int*   curC  = curR + B;                       // B
        int*   ovfRc = curC + B;                       // 1
        int*   ovfCc = ovfRc + 1;                      // 1
        int2*  ovfR  = (int2*)(ovfCc + 1);
        {   // ensure 8B alignment for int2
            size_t off = (size_t)(ovfCc + 1 - ws);
            if (off & 1) ovfR = (int2*)(ovfCc + 2);
        }
        int*   ovfC  = (int*)(ovfR + OVF_CAP);

        initc_kernel<<<(B + 255) / 256, 256, 0, stream>>>(curR, curC, ovfRc, ovfCc, B);
        part_kernel<<<nb_p, 256, 0, stream>>>(row, col, curR, curC, pairs, bufC,
                                              ovfRc, ovfR, ovfCc, ovfC, B, E);
        histo_kernel<<<B, 256, 0, stream>>>(curC, bufC, deg, (int)n);
        ovfc_deg_kernel<<<nb_ov, 256, 0, stream>>>(ovfCc, ovfC, deg);
        dinvz_kernel<<<nb_n, 256, 0, stream>>>(deg, dinv, (float4*)Bv, (float2*)Dv, (int)n);
        // bufC dead from here; Td + P region live.
        mm1_kernel<<<nb_mm, 256, 0, stream>>>(x, W1, dinv, (float4*)Td1, (int)n);

        aggp4_kernel<<<B * SPLIT, 256, 0, stream>>>(curR, pairs, (const float4*)Td1, P);
        ovf4_kernel<<<nb_ov, 256, 0, stream>>>(ovfRc, ovfR, (const float4*)Td1, Bv);
        merge1_kernel<<<nb_n, 256, 0, stream>>>(P, dinv, (const float4*)Td1, (float4*)Bv, b1, W2, (float4*)Td2, (int)n);

        aggp4_kernel<<<B * SPLIT, 256, 0, stream>>>(curR, pairs, (const float4*)Td2, P);
        ovf4_kernel<<<nb_ov, 256, 0, stream>>>(ovfRc, ovfR, (const float4*)Td2, Bv);
        merge2_kernel<<<nb_n, 256, 0, stream>>>(P, dinv, (const float4*)Td2, (const float4*)Bv, b2, W3, (float2*)Td3, (int)n);

        aggp2_kernel<<<B * SPLIT, 256, 0, stream>>>(curR, pairs, (const float2*)Td3, P);
        ovf2_kernel<<<nb_ov, 256, 0, stream>>>(ovfRc, ovfR, (const float2*)Td3, Dv);
        merge3_kernel<<<nb_n, 256, 0, stream>>>(P, dinv, (const float2*)Td3, (const float2*)Dv, b3, Wc, bc, (float*)d_out, (int)n);
    } else {
        // fallback: round-2 ELL path (proven)
        float* fws  = (float*)d_ws;
        float* A1   = fws;
        float* A2   = A1 + 4 * n;
        float* C3   = A2 + 4 * n;
        float* Bv   = C3 + 2 * n;
        float* Dv   = Bv + 4 * n;
        float* dinv = Dv + 2 * n;
        int*   cnt  = (int*)(dinv + n);
        int*   deg  = cnt + n;
        int*   ovfc = deg + n;
        int2*  ovf  = (int2*)(ovfc + 4);
        int*   slots = (int*)(ovf + OVF_CAP);

        long zc = (long)(9 * n + 4);
        zero_kernel<<<(int)((zc + 255) / 256), 256, 0, stream>>>((int*)Bv, zc);
        build_kernel<<<nb_e, 256, 0, stream>>>(row, col, deg, cnt, slots, ovfc, ovf, (int)n, E);
        dinv2_kernel<<<nb_n, 256, 0, stream>>>(deg, dinv, (int)n);
        mm1_kernel<<<nb_mm, 256, 0, stream>>>(x, W1, dinv, (float4*)A1, (int)n);
        ovf4_kernel<<<nb_ov, 256, 0, stream>>>(ovfc, ovf, (const float4*)A1, Bv);
        agg_node1<<<nb_n, 256, 0, stream>>>(cnt, slots, dinv, (const float4*)A1, (float4*)Bv, b1, W2, (float4*)A2, (int)n);
        ovf4_kernel<<<nb_ov, 256, 0, stream>>>(ovfc, ovf, (const float4*)A2, Bv);
        agg_node2<<<nb_n, 256, 0, stream>>>(cnt, slots, dinv, (const float4*)A2, (const float4*)Bv, b2, W3, (float2*)C3, (int)n);
        ovf2_kernel<<<nb_ov, 256, 0, stream>>>(ovfc, ovf, (const float2*)C3, Dv);
        agg_node3<<<nb_n, 256, 0, stream>>>(cnt, slots, dinv, (const float2*)C3, (const float2*)Dv, b3, Wc, bc, (float*)d_out, (int)n);
    }
}

// Round 6
// 401.129 us; speedup vs baseline: 1.8192x; 1.0992x over previous
//
#include <hip/hip_runtime.h>
#include <math.h>

// GCN: h = D^-1/2 (A+I) D^-1/2 (x W) + b, 3 layers + classifier.
// N = 100000 nodes, E = 3.2M edges, feats 128 -> 4 -> 4 -> 2 -> 4.
//
// Round 6: part_kernel was write-transaction-bound (175MB of 32B txns for a
// 51MB payload: interleaved 4B scatters across 391 bucket regions). Fix:
// block-local counting sort in LDS (hist -> scan -> sorted place -> dump),
// so dumps are bucket-contiguous and the coalescer merges them (~10x fewer
// write txns). Source-side copy shrinks to bytes (only c&255 needed for the
// per-bucket degree histogram). Dispatch fusion: dinv into mm1, overflow
// scan into merges; Bv/Dv and zero pass eliminated (17 -> 11 dispatches).

#define OVF_CAP 32768
#define NBMAX   512      // max buckets (n <= 131072)
#define CHUNK   4096     // edges per partition block
#define CAPB    11776    // bucket capacity (expected 8192 uniform; 1.44x)
#define SPLIT   8        // agg sub-blocks per bucket

// ---------------- fast path ----------------

__global__ __launch_bounds__(256) void initc_kernel(int* __restrict__ curR, int* __restrict__ curC,
                                                    int* __restrict__ ovfRc, int* __restrict__ ovfCc, int B) {
    int i = blockIdx.x * blockDim.x + threadIdx.x;
    if (i == 0) { *ovfRc = 0; *ovfCc = 0; }
    if (i < B) { curR[i] = i * CAPB; curC[i] = i * CAPB; }
}

// Block-local counting sort per 4096-edge chunk, two phases:
//   R: bin by r>>8, payload ((r&255)<<24)|c into pairs[] (int)
//   C: bin by c>>8, payload c&255 into bufC8[] (byte)
__global__ __launch_bounds__(256) void part_kernel(const int* __restrict__ row, const int* __restrict__ col,
                                                   int* __restrict__ curR, int* __restrict__ curC,
                                                   int* __restrict__ pairs, unsigned char* __restrict__ bufC8,
                                                   int* __restrict__ ovfRc, int2* __restrict__ ovfR,
                                                   int* __restrict__ ovfCc, int* __restrict__ ovfC,
                                                   int B, int E) {
    __shared__ int hist[NBMAX];      // counts, then per-bucket cursor
    __shared__ int gbase[NBMAX];     // reserved global base
    __shared__ int sA[NBMAX];        // scan ping / final local base
    __shared__ int sB[NBMAX];        // scan pong
    __shared__ int sVal[CHUNK];
    __shared__ int sGpos[CHUNK];
    const int t = threadIdx.x;
    const long e0 = (long)blockIdx.x * CHUNK;
    int cnt_ch = (int)(E - e0); if (cnt_ch > CHUNK) cnt_ch = CHUNK; if (cnt_ch < 0) cnt_ch = 0;

    for (int side = 0; side < 2; ++side) {
        // --- histogram ---
        for (int i = t; i < NBMAX; i += 256) hist[i] = 0;
        __syncthreads();
        for (int k = t; k < cnt_ch; k += 256) {
            long e = e0 + k;
            int key = side == 0 ? row[e] : col[e];
            atomicAdd(&hist[key >> 8], 1);
        }
        __syncthreads();
        // --- inclusive scan (Hillis-Steele, NBMAX wide) ---
        for (int i = t; i < NBMAX; i += 256) sA[i] = hist[i];
        __syncthreads();
        int* a = sA; int* b = sB;
        for (int off = 1; off < NBMAX; off <<= 1) {
            for (int i = t; i < NBMAX; i += 256)
                b[i] = a[i] + (i >= off ? a[i - off] : 0);
            __syncthreads();
            int* tmp = a; a = b; b = tmp;
        }
        // a[] holds inclusive scan. reserve global runs; make exclusive base; reset cursor.
        int* cur = (side == 0) ? curR : curC;
        for (int i = t; i < NBMAX; i += 256) {
            int cntb = hist[i];
            gbase[i] = cntb ? atomicAdd(&cur[i], cntb) : 0;
            b[i] = a[i] - cntb;              // exclusive local base (in b[])
            hist[i] = 0;                     // reuse as cursor
        }
        __syncthreads();
        // --- sorted placement into LDS ---
        for (int k = t; k < cnt_ch; k += 256) {
            long e = e0 + k;
            int r = row[e], c = col[e];
            int key = side == 0 ? r : c;
            int bk = key >> 8;
            int rank = atomicAdd(&hist[bk], 1);
            int lpos = b[bk] + rank;
            int gpos = gbase[bk] + rank;
            if (gpos < (bk + 1) * CAPB) {
                sVal[lpos] = side == 0 ? (((r & 255) << 24) | c) : c;
                sGpos[lpos] = gpos;
            } else {
                sVal[lpos] = 0;
                sGpos[lpos] = -1;
                if (side == 0) {
                    int i = atomicAdd(ovfRc, 1);
                    if (i < OVF_CAP) ovfR[i] = make_int2(r, c);
                } else {
                    int i = atomicAdd(ovfCc, 1);
                    if (i < OVF_CAP) ovfC[i] = c;
                }
            }
        }
        __syncthreads();
        // --- coalesced dump ---
        if (side == 0) {
            for (int k = t; k < cnt_ch; k += 256) {
                int g = sGpos[k];
                if (g >= 0) pairs[g] = sVal[k];
            }
        } else {
            for (int k = t; k < cnt_ch; k += 256) {
                int g = sGpos[k];
                if (g >= 0) bufC8[g] = (unsigned char)(sVal[k] & 255);
            }
        }
        __syncthreads();
    }
}

// deg from byte-binned copy: per-bucket LDS histogram, sequential write.
__global__ __launch_bounds__(256) void histo_kernel(const int* __restrict__ curC, const unsigned char* __restrict__ bufC8,
                                                    int* __restrict__ deg, int n) {
    __shared__ int h[256];
    const int b = blockIdx.x, t = threadIdx.x;
    h[t] = 0;
    __syncthreads();
    int base = b * CAPB;
    int cnt = curC[b] - base; if (cnt > CAPB) cnt = CAPB; if (cnt < 0) cnt = 0;
    for (int k = t; k < cnt; k += 256) atomicAdd(&h[bufC8[base + k]], 1);
    __syncthreads();
    int v = b * 256 + t;
    if (v < n) deg[v] = h[t];
}

__global__ __launch_bounds__(256) void ovfc_deg_kernel(const int* __restrict__ ovfCc, const int* __restrict__ ovfC,
                                                       int* __restrict__ deg) {
    int i = blockIdx.x * blockDim.x + threadIdx.x;
    int m = *ovfCc; if (m > OVF_CAP) m = OVF_CAP;
    if (i >= m) return;
    atomicAdd(&deg[ovfC[i]], 1);
}

// x [n,128] @ W1 [128,4] -> Td1 [n,4], pre-scaled by dinv[v]; also writes dinv.
__global__ __launch_bounds__(256) void mm1_kernel(const float* __restrict__ x, const float* __restrict__ W1,
                                                  const int* __restrict__ deg, float* __restrict__ dinv,
                                                  float4* __restrict__ Td1, int n) {
    int gid  = blockIdx.x * blockDim.x + threadIdx.x;
    int lane = threadIdx.x & 63;
    int v    = gid >> 6;
    if (v >= n) return;
    float2 xv = ((const float2*)x)[(size_t)v * 64 + lane];
    float4 wa = ((const float4*)W1)[2 * lane];
    float4 wb = ((const float4*)W1)[2 * lane + 1];
    float p0 = xv.x * wa.x + xv.y * wb.x;
    float p1 = xv.x * wa.y + xv.y * wb.y;
    float p2 = xv.x * wa.z + xv.y * wb.z;
    float p3 = xv.x * wa.w + xv.y * wb.w;
#pragma unroll
    for (int off = 32; off > 0; off >>= 1) {
        p0 += __shfl_xor(p0, off);
        p1 += __shfl_xor(p1, off);
        p2 += __shfl_xor(p2, off);
        p3 += __shfl_xor(p3, off);
    }
    if (lane == 0) {
        float d = rsqrtf((float)(deg[v] + 1));
        dinv[v] = d;
        Td1[v] = make_float4(p0 * d, p1 * d, p2 * d, p3 * d);
    }
}

// agg partial pass, 4-feat: sub-block (b,s) accumulates its slice of bucket b
// into LDS, dumps dense partial (coalesced). grid = B*SPLIT.
__global__ __launch_bounds__(256) void aggp4_kernel(const int* __restrict__ curR, const int* __restrict__ pairs,
                                                    const float4* __restrict__ Td, float* __restrict__ P) {
    __shared__ float acc[1024];
    const int t = threadIdx.x;
    const int b = blockIdx.x >> 3, s = blockIdx.x & 7;
    acc[t] = 0.f; acc[256 + t] = 0.f; acc[512 + t] = 0.f; acc[768 + t] = 0.f;
    __syncthreads();
    int base = b * CAPB;
    int cnt = curR[b] - base; if (cnt > CAPB) cnt = CAPB; if (cnt < 0) cnt = 0;
    int lo = base + (int)(((long)cnt * s) >> 3);
    int hi = base + (int)(((long)cnt * (s + 1)) >> 3);
    for (int k = lo + t; k < hi; k += 256) {
        int p = pairs[k];
        int c = p & 0xFFFFFF;
        int rl = ((unsigned)p) >> 24;
        float4 tv = Td[c];
        atomicAdd(&acc[rl],       tv.x);
        atomicAdd(&acc[256 + rl], tv.y);
        atomicAdd(&acc[512 + rl], tv.z);
        atomicAdd(&acc[768 + rl], tv.w);
    }
    __syncthreads();
    float* Pb = P + ((size_t)blockIdx.x << 10);
    Pb[t] = acc[t]; Pb[256 + t] = acc[256 + t]; Pb[512 + t] = acc[512 + t]; Pb[768 + t] = acc[768 + t];
}

// 2-feat variant for layer 3.
__global__ __launch_bounds__(256) void aggp2_kernel(const int* __restrict__ curR, const int* __restrict__ pairs,
                                                    const float2* __restrict__ Td, float* __restrict__ P) {
    __shared__ float acc[512];
    const int t = threadIdx.x;
    const int b = blockIdx.x >> 3, s = blockIdx.x & 7;
    acc[t] = 0.f; acc[256 + t] = 0.f;
    __syncthreads();
    int base = b * CAPB;
    int cnt = curR[b] - base; if (cnt > CAPB) cnt = CAPB; if (cnt < 0) cnt = 0;
    int lo = base + (int)(((long)cnt * s) >> 3);
    int hi = base + (int)(((long)cnt * (s + 1)) >> 3);
    for (int k = lo + t; k < hi; k += 256) {
        int p = pairs[k];
        int c = p & 0xFFFFFF;
        int rl = ((unsigned)p) >> 24;
        float2 tv = Td[c];
        atomicAdd(&acc[rl],       tv.x);
        atomicAdd(&acc[256 + rl], tv.y);
    }
    __syncthreads();
    float* Pb = P + ((size_t)blockIdx.x << 9);
    Pb[t] = acc[t]; Pb[256 + t] = acc[256 + t];
}

// merge 8 partials + overflow(rare) + layer-1 epilogue; Td2 = (h1@W2)*dinv.
__global__ __launch_bounds__(256) void merge1_kernel(const float* __restrict__ P, const float* __restrict__ dinv,
                                                     const float4* __restrict__ Td1,
                                                     const int* __restrict__ ovfRc, const int2* __restrict__ ovfR,
                                                     const float* __restrict__ b1, const float* __restrict__ W2,
                                                     float4* __restrict__ Td2, int n) {
    const int t = threadIdx.x;
    const int v = blockIdx.x * 256 + t;
    if (v >= n) return;
    const float* Pb = P + ((size_t)blockIdx.x << 13);
    float sx = 0.f, sy = 0.f, sz = 0.f, sw = 0.f;
#pragma unroll
    for (int s = 0; s < SPLIT; ++s) {
        sx += Pb[s * 1024 + t];
        sy += Pb[s * 1024 + 256 + t];
        sz += Pb[s * 1024 + 512 + t];
        sw += Pb[s * 1024 + 768 + t];
    }
    int m = *ovfRc; if (m > OVF_CAP) m = OVF_CAP;
    for (int i = 0; i < m; ++i) {                    // normally m == 0
        int2 rc = ovfR[i];
        if (rc.x == v) { float4 tv = Td1[rc.y]; sx += tv.x; sy += tv.y; sz += tv.z; sw += tv.w; }
    }
    float4 t0 = Td1[v];                              // self-loop
    sx += t0.x; sy += t0.y; sz += t0.z; sw += t0.w;
    float d = dinv[v];
    float h0 = tanhf(d * sx + b1[0]);
    float h1 = tanhf(d * sy + b1[1]);
    float h2 = tanhf(d * sz + b1[2]);
    float h3 = tanhf(d * sw + b1[3]);
    float4 o;
    o.x = (h0 * W2[0] + h1 * W2[4] + h2 * W2[8]  + h3 * W2[12]) * d;
    o.y = (h0 * W2[1] + h1 * W2[5] + h2 * W2[9]  + h3 * W2[13]) * d;
    o.z = (h0 * W2[2] + h1 * W2[6] + h2 * W2[10] + h3 * W2[14]) * d;
    o.w = (h0 * W2[3] + h1 * W2[7] + h2 * W2[11] + h3 * W2[15]) * d;
    Td2[v] = o;
}

__global__ __launch_bounds__(256) void merge2_kernel(const float* __restrict__ P, const float* __restrict__ dinv,
                                                     const float4* __restrict__ Td2,
                                                     const int* __restrict__ ovfRc, const int2* __restrict__ ovfR,
                                                     const float* __restrict__ b2, const float* __restrict__ W3,
                                                     float2* __restrict__ Td3, int n) {
    const int t = threadIdx.x;
    const int v = blockIdx.x * 256 + t;
    if (v >= n) return;
    const float* Pb = P + ((size_t)blockIdx.x << 13);
    float sx = 0.f, sy = 0.f, sz = 0.f, sw = 0.f;
#pragma unroll
    for (int s = 0; s < SPLIT; ++s) {
        sx += Pb[s * 1024 + t];
        sy += Pb[s * 1024 + 256 + t];
        sz += Pb[s * 1024 + 512 + t];
        sw += Pb[s * 1024 + 768 + t];
    }
    int m = *ovfRc; if (m > OVF_CAP) m = OVF_CAP;
    for (int i = 0; i < m; ++i) {
        int2 rc = ovfR[i];
        if (rc.x == v) { float4 tv = Td2[rc.y]; sx += tv.x; sy += tv.y; sz += tv.z; sw += tv.w; }
    }
    float4 t0 = Td2[v];
    sx += t0.x; sy += t0.y; sz += t0.z; sw += t0.w;
    float d = dinv[v];
    float h0 = tanhf(d * sx + b2[0]);
    float h1 = tanhf(d * sy + b2[1]);
    float h2 = tanhf(d * sz + b2[2]);
    float h3 = tanhf(d * sw + b2[3]);
    float2 o;
    o.x = (h0 * W3[0] + h1 * W3[2] + h2 * W3[4] + h3 * W3[6]) * d;
    o.y = (h0 * W3[1] + h1 * W3[3] + h2 * W3[5] + h3 * W3[7]) * d;
    Td3[v] = o;
}

__global__ __launch_bounds__(256) void merge3_kernel(const float* __restrict__ P, const float* __restrict__ dinv,
                                                     const float2* __restrict__ Td3,
                                                     const int* __restrict__ ovfRc, const int2* __restrict__ ovfR,
                                                     const float* __restrict__ b3, const float* __restrict__ Wc,
                                                     const float* __restrict__ bc, float* __restrict__ out, int n) {
    const int t = threadIdx.x;
    const int v = blockIdx.x * 256 + t;
    if (v >= n) return;
    const float* Pb = P + ((size_t)blockIdx.x << 12);
    float sx = 0.f, sy = 0.f;
#pragma unroll
    for (int s = 0; s < SPLIT; ++s) {
        sx += Pb[s * 512 + t];
        sy += Pb[s * 512 + 256 + t];
    }
    int m = *ovfRc; if (m > OVF_CAP) m = OVF_CAP;
    for (int i = 0; i < m; ++i) {
        int2 rc = ovfR[i];
        if (rc.x == v) { float2 tv = Td3[rc.y]; sx += tv.x; sy += tv.y; }
    }
    float2 t0 = Td3[v];
    sx += t0.x; sy += t0.y;
    float d = dinv[v];
    float h0 = tanhf(d * sx + b3[0]);
    float h1 = tanhf(d * sy + b3[1]);
    float4 o;
    o.x = h0 * Wc[0] + h1 * Wc[4] + bc[0];
    o.y = h0 * Wc[1] + h1 * Wc[5] + bc[1];
    o.z = h0 * Wc[2] + h1 * Wc[6] + bc[2];
    o.w = h0 * Wc[3] + h1 * Wc[7] + bc[3];
    ((float4*)out)[v] = o;
    ((float2*)(out + (size_t)n * 4))[v] = make_float2(h0, h1);
}

// ---------------- fallback path (round-2, proven) ----------------

#define ELL_C 64

__global__ __launch_bounds__(256) void zero_kernel(int* __restrict__ p, long count) {
    long i = (long)blockIdx.x * blockDim.x + threadIdx.x;
    if (i < count) p[i] = 0;
}
__global__ __launch_bounds__(256) void build_kernel(const int* __restrict__ row, const int* __restrict__ col,
                                                    int* __restrict__ deg, int* __restrict__ cnt,
                                                    int* __restrict__ slots, int* __restrict__ ovfc,
                                                    int2* __restrict__ ovf, int n, int E) {
    int e = blockIdx.x * blockDim.x + threadIdx.x;
    if (e >= E) return;
    int r = row[e], c = col[e];
    atomicAdd(&deg[c], 1);
    int pos = atomicAdd(&cnt[r], 1);
    if (pos < ELL_C) {
        slots[(size_t)pos * n + r] = c;
    } else {
        int i = atomicAdd(ovfc, 1);
        if (i < OVF_CAP) ovf[i] = make_int2(r, c);
    }
}
__global__ __launch_bounds__(256) void fb_mm1(const float* __restrict__ x, const float* __restrict__ W1,
                                              const int* __restrict__ deg, float* __restrict__ dinv,
                                              float4* __restrict__ A, int n) {
    int gid  = blockIdx.x * blockDim.x + threadIdx.x;
    int lane = threadIdx.x & 63;
    int v    = gid >> 6;
    if (v >= n) return;
    float2 xv = ((const float2*)x)[(size_t)v * 64 + lane];
    float4 wa = ((const float4*)W1)[2 * lane];
    float4 wb = ((const float4*)W1)[2 * lane + 1];
    float p0 = xv.x * wa.x + xv.y * wb.x;
    float p1 = xv.x * wa.y + xv.y * wb.y;
    float p2 = xv.x * wa.z + xv.y * wb.z;
    float p3 = xv.x * wa.w + xv.y * wb.w;
#pragma unroll
    for (int off = 32; off > 0; off >>= 1) {
        p0 += __shfl_xor(p0, off); p1 += __shfl_xor(p1, off);
        p2 += __shfl_xor(p2, off); p3 += __shfl_xor(p3, off);
    }
    if (lane == 0) {
        float d = rsqrtf((float)(deg[v] + 1));
        dinv[v] = d;
        A[v] = make_float4(p0 * d, p1 * d, p2 * d, p3 * d);
    }
}
__global__ __launch_bounds__(256) void ovf4_kernel(const int* __restrict__ ovfc, const int2* __restrict__ ovf,
                                                   const float4* __restrict__ Td, float* __restrict__ B) {
    int e = blockIdx.x * blockDim.x + threadIdx.x;
    int m = *ovfc; if (m > OVF_CAP) m = OVF_CAP;
    if (e >= m) return;
    int2 rc = ovf[e];
    float4 t = Td[rc.y];
    atomicAdd(&B[rc.x * 4 + 0], t.x);
    atomicAdd(&B[rc.x * 4 + 1], t.y);
    atomicAdd(&B[rc.x * 4 + 2], t.z);
    atomicAdd(&B[rc.x * 4 + 3], t.w);
}
__global__ __launch_bounds__(256) void ovf2_kernel(const int* __restrict__ ovfc, const int2* __restrict__ ovf,
                                                   const float2* __restrict__ Td, float* __restrict__ D) {
    int e = blockIdx.x * blockDim.x + threadIdx.x;
    int m = *ovfc; if (m > OVF_CAP) m = OVF_CAP;
    if (e >= m) return;
    int2 rc = ovf[e];
    float2 t = Td[rc.y];
    atomicAdd(&D[rc.x * 2 + 0], t.x);
    atomicAdd(&D[rc.x * 2 + 1], t.y);
}
__global__ __launch_bounds__(256) void agg_node1(const int* __restrict__ cnt, const int* __restrict__ slots,
                                                 const float* __restrict__ dinv, const float4* __restrict__ Td1,
                                                 float4* __restrict__ B, const float* __restrict__ b1,
                                                 const float* __restrict__ W2, float4* __restrict__ Td2, int n) {
    int v = blockIdx.x * blockDim.x + threadIdx.x;
    if (v >= n) return;
    int k = cnt[v]; if (k > ELL_C) k = ELL_C;
    float4 s = B[v];
    for (int j = 0; j < k; ++j) {
        int c = slots[(size_t)j * n + v];
        float4 t = Td1[c];
        s.x += t.x; s.y += t.y; s.z += t.z; s.w += t.w;
    }
    float4 t0 = Td1[v];
    s.x += t0.x; s.y += t0.y; s.z += t0.z; s.w += t0.w;
    float d = dinv[v];
    float h0 = tanhf(d * s.x + b1[0]);
    float h1 = tanhf(d * s.y + b1[1]);
    float h2 = tanhf(d * s.z + b1[2]);
    float h3 = tanhf(d * s.w + b1[3]);
    float4 o;
    o.x = (h0 * W2[0] + h1 * W2[4] + h2 * W2[8]  + h3 * W2[12]) * d;
    o.y = (h0 * W2[1] + h1 * W2[5] + h2 * W2[9]  + h3 * W2[13]) * d;
    o.z = (h0 * W2[2] + h1 * W2[6] + h2 * W2[10] + h3 * W2[14]) * d;
    o.w = (h0 * W2[3] + h1 * W2[7] + h2 * W2[11] + h3 * W2[15]) * d;
    Td2[v] = o;
    B[v] = make_float4(0.f, 0.f, 0.f, 0.f);
}
__global__ __launch_bounds__(256) void agg_node2(const int* __restrict__ cnt, const int* __restrict__ slots,
                                                 const float* __restrict__ dinv, const float4* __restrict__ Td2,
                                                 const float4* __restrict__ B, const float* __restrict__ b2,
                                                 const float* __restrict__ W3, float2* __restrict__ Td3, int n) {
    int v = blockIdx.x * blockDim.x + threadIdx.x;
    if (v >= n) return;
    int k = cnt[v]; if (k > ELL_C) k = ELL_C;
    float4 s = B[v];
    for (int j = 0; j < k; ++j) {
        int c = slots[(size_t)j * n + v];
        float4 t = Td2[c];
        s.x += t.x; s.y += t.y; s.z += t.z; s.w += t.w;
    }
    float4 t0 = Td2[v];
    s.x += t0.x; s.y += t0.y; s.z += t0.z; s.w += t0.w;
    float d = dinv[v];
    float h0 = tanhf(d * s.x + b2[0]);
    float h1 = tanhf(d * s.y + b2[1]);
    float h2 = tanhf(d * s.z + b2[2]);
    float h3 = tanhf(d * s.w + b2[3]);
    float2 o;
    o.x = (h0 * W3[0] + h1 * W3[2] + h2 * W3[4] + h3 * W3[6]) * d;
    o.y = (h0 * W3[1] + h1 * W3[3] + h2 * W3[5] + h3 * W3[7]) * d;
    Td3[v] = o;
}
__global__ __launch_bounds__(256) void agg_node3(const int* __restrict__ cnt, const int* __restrict__ slots,
                                                 const float* __restrict__ dinv, const float2* __restrict__ Td3,
                                                 const float2* __restrict__ D, const float* __restrict__ b3,
                                                 const float* __restrict__ Wc, const float* __restrict__ bc,
                                                 float* __restrict__ out, int n) {
    int v = blockIdx.x * blockDim.x + threadIdx.x;
    if (v >= n) return;
    int k = cnt[v]; if (k > ELL_C) k = ELL_C;
    float2 s = D[v];
    for (int j = 0; j < k; ++j) {
        int c = slots[(size_t)j * n + v];
        float2 t = Td3[c];
        s.x += t.x; s.y += t.y;
    }
    float2 t0 = Td3[v];
    s.x += t0.x; s.y += t0.y;
    float d = dinv[v];
    float h0 = tanhf(d * s.x + b3[0]);
    float h1 = tanhf(d * s.y + b3[1]);
    float4 o;
    o.x = h0 * Wc[0] + h1 * Wc[4] + bc[0];
    o.y = h0 * Wc[1] + h1 * Wc[5] + bc[1];
    o.z = h0 * Wc[2] + h1 * Wc[6] + bc[2];
    o.w = h0 * Wc[3] + h1 * Wc[7] + bc[3];
    ((float4*)out)[v] = o;
    ((float2*)(out + (size_t)n * 4))[v] = make_float2(h0, h1);
}

extern "C" void kernel_launch(void* const* d_in, const int* in_sizes, int n_in,
                              void* d_out, int out_size, void* d_ws, size_t ws_size,
                              hipStream_t stream) {
    const float* x  = (const float*)d_in[0];
    const int*   ei = (const int*)  d_in[1];
    const float* W1 = (const float*)d_in[2];
    const float* b1 = (const float*)d_in[3];
    const float* W2 = (const float*)d_in[4];
    const float* b2 = (const float*)d_in[5];
    const float* W3 = (const float*)d_in[6];
    const float* b3 = (const float*)d_in[7];
    const float* Wc = (const float*)d_in[8];
    const float* bc = (const float*)d_in[9];

    const size_t n = (size_t)(in_sizes[0] / 128);
    const int    E = in_sizes[1] / 2;
    const int* row = ei;       // destinations (segment ids)
    const int* col = ei + E;   // sources (gather)

    const int B     = (int)((n + 255) >> 8);
    const int nb_n  = (int)((n + 255) / 256);
    const int nb_e  = (E + 255) / 256;
    const int nb_mm = (int)((n * 64 + 255) / 256);
    const int nb_ov = OVF_CAP / 256;
    const int nb_p  = (E + CHUNK - 1) / CHUNK;

    int* ws = (int*)d_ws;

    // fast-path layout (ints):
    // pairs B*CAPB | U max(ceil(B*CAPB/4), 10n + B*SPLIT*1024) | dinv n | deg n |
    // curR B | curC B | ovfRc 1 | ovfCc 1 (+pad) | ovfR 2*OVF_CAP | ovfC OVF_CAP
    size_t uni = ((size_t)B * CAPB + 3) / 4;
    size_t td_plus_p = 10 * n + (size_t)B * SPLIT * 1024;
    if (uni < td_plus_p) uni = td_plus_p;
    size_t need_fast = ((size_t)B * CAPB + uni + 2 * n + 2 * (size_t)B + 4 + 3 * OVF_CAP) * 4 + 64;

    if (ws_size >= need_fast && n <= (1u << 24) && B <= NBMAX) {
        int*   pairs = ws;
        int*   U     = pairs + (size_t)B * CAPB;
        float* Td1   = (float*)U;                      // 4n
        float* Td2   = Td1 + 4 * n;                    // 4n
        float* Td3   = Td2 + 4 * n;                    // 2n
        float* P     = Td3 + 2 * n;                    // B*SPLIT*1024
        unsigned char* bufC8 = (unsigned char*)U;      // dead after histo (aliases Td)
        float* dinv  = (float*)(U + uni);              // n
        int*   deg   = (int*)(dinv + n);               // n
        int*   curR  = deg + n;                        // B
        int*   curC  = curR + B;                       // B
        int*   ovfRc = curC + B;                       // 1
        int*   ovfCc = ovfRc + 1;                      // 1
        int2*  ovfR  = (int2*)(ovfCc + 1);
        {   // ensure 8B alignment for int2
            size_t off = (size_t)(ovfCc + 1 - ws);
            if (off & 1) ovfR = (int2*)(ovfCc + 2);
        }
        int*   ovfC  = (int*)(ovfR + OVF_CAP);

        initc_kernel<<<(B + 255) / 256, 256, 0, stream>>>(curR, curC, ovfRc, ovfCc, B);
        part_kernel<<<nb_p, 256, 0, stream>>>(row, col, curR, curC, pairs, bufC8,
                                              ovfRc, ovfR, ovfCc, ovfC, B, E);
        histo_kernel<<<B, 256, 0, stream>>>(curC, bufC8, deg, (int)n);
        ovfc_deg_kernel<<<nb_ov, 256, 0, stream>>>(ovfCc, ovfC, deg);
        // bufC8 dead from here; Td + P region live.
        mm1_kernel<<<nb_mm, 256, 0, stream>>>(x, W1, deg, dinv, (float4*)Td1, (int)n);

        aggp4_kernel<<<B * SPLIT, 256, 0, stream>>>(curR, pairs, (const float4*)Td1, P);
        merge1_kernel<<<nb_n, 256, 0, stream>>>(P, dinv, (const float4*)Td1, ovfRc, ovfR, b1, W2, (float4*)Td2, (int)n);

        aggp4_kernel<<<B * SPLIT, 256, 0, stream>>>(curR, pairs, (const float4*)Td2, P);
        merge2_kernel<<<nb_n, 256, 0, stream>>>(P, dinv, (const float4*)Td2, ovfRc, ovfR, b2, W3, (float2*)Td3, (int)n);

        aggp2_kernel<<<B * SPLIT, 256, 0, stream>>>(curR, pairs, (const float2*)Td3, P);
        merge3_kernel<<<nb_n, 256, 0, stream>>>(P, dinv, (const float2*)Td3, ovfRc, ovfR, b3, Wc, bc, (float*)d_out, (int)n);
    } else {
        // fallback: round-2 ELL path (proven)
        float* fws  = (float*)d_ws;
        float* A1   = fws;
        float* A2   = A1 + 4 * n;
        float* C3   = A2 + 4 * n;
        float* Bv   = C3 + 2 * n;
        float* Dv   = Bv + 4 * n;
        float* dinv = Dv + 2 * n;
        int*   cnt  = (int*)(dinv + n);
        int*   deg  = cnt + n;
        int*   ovfc = deg + n;
        int2*  ovf  = (int2*)(ovfc + 4);
        int*   slots = (int*)(ovf + OVF_CAP);

        long zc = (long)(9 * n + 4);
        zero_kernel<<<(int)((zc + 255) / 256), 256, 0, stream>>>((int*)Bv, zc);
        build_kernel<<<nb_e, 256, 0, stream>>>(row, col, deg, cnt, slots, ovfc, ovf, (int)n, E);
        fb_mm1<<<nb_mm, 256, 0, stream>>>(x, W1, deg, dinv, (float4*)A1, (int)n);
        ovf4_kernel<<<nb_ov, 256, 0, stream>>>(ovfc, ovf, (const float4*)A1, Bv);
        agg_node1<<<nb_n, 256, 0, stream>>>(cnt, slots, dinv, (const float4*)A1, (float4*)Bv, b1, W2, (float4*)A2, (int)n);
        ovf4_kernel<<<nb_ov, 256, 0, stream>>>(ovfc, ovf, (const float4*)A2, Bv);
        agg_node2<<<nb_n, 256, 0, stream>>>(cnt, slots, dinv, (const float4*)A2, (const float4*)Bv, b2, W3, (float2*)C3, (int)n);
        ovf2_kernel<<<nb_ov, 256, 0, stream>>>(ovfc, ovf, (const float2*)C3, Dv);
        agg_node3<<<nb_n, 256, 0, stream>>>(cnt, slots, dinv, (const float2*)C3, (const float2*)Dv, b3, Wc, bc, (float*)d_out, (int)n);
    }
}